// Round 10
// baseline (8600.390 us; speedup 1.0000x reference)
//
#include <hip/hip_runtime.h>
#include <hip/hip_bf16.h>
#include <cstdint>
#include <cstddef>

#define B_DIM   64
#define T_DIM   256
#define ICD_DIM 2000
#define H_DIM   384
#define CH_DIM  128
#define W_WIN   10
#define M_DIM   (B_DIM * T_DIM)         // 16384
#define XO_DIM  1542                    // 4H + 2L
#define XO_PAD  1664                    // 13*128
#define K_X     2016                    // 2000 padded to 63*32
#define KCONV   3840                    // H*W
#define N_OUTP  2048                    // 2000 padded to 16*128

typedef unsigned short ushort_t;
typedef unsigned int   uint_t;
typedef __attribute__((ext_vector_type(8))) short short8;
typedef __attribute__((ext_vector_type(4))) float f32x4;
typedef __attribute__((ext_vector_type(2))) _Float16 f16x2;

__device__ __forceinline__ ushort_t f2bf(float v) {
    __hip_bfloat16 b = __float2bfloat16(v);
    ushort_t u; __builtin_memcpy(&u, &b, 2); return u;
}
__device__ __forceinline__ float bf2f(ushort_t u) {
    __hip_bfloat16 b; __builtin_memcpy(&b, &u, 2); return __bfloat162float(b);
}
__device__ __forceinline__ float sigmoidf_(float x) { return 1.f / (1.f + expf(-x)); }
__device__ __forceinline__ f16x2 asf16x2(uint_t u) { f16x2 h; __builtin_memcpy(&h, &u, 4); return h; }
__device__ __forceinline__ uint_t pkf16(float a, float b) {
    f16x2 h; h.x = (_Float16)a; h.y = (_Float16)b;
    uint_t u; __builtin_memcpy(&u, &h, 4); return u;
}
__device__ __forceinline__ float dot2f(uint_t a, uint_t b, float acc) {
#if __has_builtin(__builtin_amdgcn_fdot2)
    return __builtin_amdgcn_fdot2(asf16x2(a), asf16x2(b), acc, false);
#else
    f16x2 ha = asf16x2(a), hb = asf16x2(b);
    return acc + (float)ha.x * (float)hb.x + (float)ha.y * (float)hb.y;
#endif
}

// async global -> LDS, 16 bytes per lane (wave-uniform base + lane*16)
#define GLOAD_LDS16(g, l) __builtin_amdgcn_global_load_lds( \
    (const __attribute__((address_space(1))) void*)(g),     \
    (__attribute__((address_space(3))) void*)(l), 16, 0, 0)

// ---------------------------------------------------------------------------
// prep kernels
// ---------------------------------------------------------------------------
__global__ void prep_dia(const float* __restrict__ dia_w, ushort_t* __restrict__ hi)
{
    int id = blockIdx.x * 256 + threadIdx.x;
    if (id >= H_DIM * K_X) return;
    int n = id / K_X, k = id - n * K_X;
    hi[id] = f2bf((k < ICD_DIM) ? dia_w[(size_t)k * H_DIM + n] : 0.f);
}
__global__ void prep_ker(const float* __restrict__ kernel_w, ushort_t* __restrict__ hi)
{
    int id = blockIdx.x * 256 + threadIdx.x;
    if (id >= XO_PAD * H_DIM) return;
    int n = id / H_DIM, k = id - n * H_DIM;
    hi[id] = f2bf((n < XO_DIM) ? kernel_w[(size_t)k * XO_DIM + n] : 0.f);
}
__global__ void prep_conv(const float* __restrict__ conv_w, ushort_t* __restrict__ bt)
{
    int id = blockIdx.x * 256 + threadIdx.x;
    if (id >= H_DIM * KCONV) return;
    int o = id / KCONV, k = id - o * KCONV;
    int w = k / H_DIM, h = k - w * H_DIM;
    bt[id] = f2bf(conv_w[((size_t)o * H_DIM + h) * W_WIN + w]);
}
__global__ void prep_out(const float* __restrict__ out_w, ushort_t* __restrict__ bt)
{
    int id = blockIdx.x * 256 + threadIdx.x;
    if (id >= N_OUTP * H_DIM) return;
    int n = id / H_DIM, k = id - n * H_DIM;
    bt[id] = f2bf((n < ICD_DIM) ? out_w[(size_t)k * ICD_DIM + n] : 0.f);
}
__global__ void prep_misc(const float* __restrict__ kernel_w, const float* __restrict__ kernel_b,
                          const float* __restrict__ rec_w, const float* __restrict__ rec_b,
                          const float* __restrict__ out_b,
                          float* __restrict__ bias2p, float* __restrict__ outbp)
{
    int j = blockIdx.x * 256 + threadIdx.x;
    if (j < XO_PAD)
        bias2p[j] = (j < XO_DIM) ? (kernel_w[(size_t)H_DIM * XO_DIM + j] + kernel_b[j]
                                  + rec_w[(size_t)H_DIM * XO_DIM + j] + rec_b[j]) : 0.f;
    if (j < N_OUTP)
        outbp[j] = (j < ICD_DIM) ? out_b[j] : 0.f;
}
// rec_w gate cols -> recg[((q*2+half)*96 + kk)*384 + cg]; master cols -> recm[mc*192 + p]
__global__ void prep_rec2(const float* __restrict__ rec_w, uint_t* __restrict__ recg, uint_t* __restrict__ recm)
{
    int id = blockIdx.x * 256 + threadIdx.x;
    const int NG = 4 * 2 * 96 * 384;
    if (id < NG) {
        int cg = id % 384;
        int kk = (id / 384) % 96;
        int half = (id / (384 * 96)) & 1;
        int q = id / (384 * 96 * 2);
        int p = half * 96 + kk;
        int j = 6 + (cg >> 5) * 128 + q * 32 + (cg & 31);
        recg[id] = pkf16(rec_w[(size_t)(2 * p) * XO_DIM + j], rec_w[(size_t)(2 * p + 1) * XO_DIM + j]);
    } else if (id < NG + 6 * 192) {
        int id2 = id - NG;
        int mc = id2 / 192, p = id2 % 192;
        recm[id2] = pkf16(rec_w[(size_t)(2 * p) * XO_DIM + mc], rec_w[(size_t)(2 * p + 1) * XO_DIM + mc]);
    }
}
// scale_w (384,64) -> f16 k-pairs [192][64]; rescale_w (64,384) -> f16 k-pairs [32][384]
__global__ void prep_sr(const float* __restrict__ scale_w, const float* __restrict__ rescale_w,
                        uint_t* __restrict__ s2, uint_t* __restrict__ r2)
{
    int id = blockIdx.x * 256 + threadIdx.x;
    if (id < 192 * 64) {
        int k = id / 64, o = id % 64;
        s2[id] = pkf16(scale_w[(size_t)(2 * k) * 64 + o], scale_w[(size_t)(2 * k + 1) * 64 + o]);
    } else if (id < 192 * 64 + 32 * 384) {
        int id2 = id - 192 * 64;
        int k = id2 / 384, j = id2 % 384;
        r2[id2] = pkf16(rescale_w[(size_t)(2 * k) * 384 + j], rescale_w[(size_t)(2 * k + 1) * 384 + j]);
    }
}

// ---------------------------------------------------------------------------
// MFMA bf16 GEMM, 128x128 tile, BK=32, 256 threads.  (MODE 0 and 2)
// MODE 0: A = x (f32 -> bf16), B = dia_hi, out Ehi/Elo split  (1 pass)
// MODE 2: A = local_h synth, B = convT, fused theme epilogue  (1 pass)
// ---------------------------------------------------------------------------
template<int MODE>
__global__ __launch_bounds__(256)
void mfma_gemm(const float* __restrict__ Af,
               const ushort_t* __restrict__ Bh,
               ushort_t* __restrict__ Cb,
               ushort_t* __restrict__ Ehi, ushort_t* __restrict__ Elo,
               const float* __restrict__ bias,
               const ushort_t* __restrict__ theme,
               const float* __restrict__ hall, const float* __restrict__ ldwp,
               int ksteps, int kdim)
{
    __shared__ ushort_t AhS[4096];
    __shared__ ushort_t BhS[4096];

    const int tid = threadIdx.x;
    const int rc = tid & 127, kh = tid >> 7;
    const int m0 = blockIdx.y * 128, n0 = blockIdx.x * 128;
    const int kq0 = kh * 2;

    const int lane = tid & 63, wid = tid >> 6;
    const int wm = wid >> 1, wn = wid & 1;
    const int l15 = lane & 15, lkq = lane >> 4;

    f32x4 acc[4][4];
#pragma unroll
    for (int i = 0; i < 4; ++i)
#pragma unroll
        for (int j = 0; j < 4; ++j)
#pragma unroll
            for (int q = 0; q < 4; ++q) acc[i][j][q] = 0.f;

    for (int ks = 0; ks < ksteps; ++ks) {
        const int k16 = ks * 32 + kh * 16;
        __syncthreads();

        // ---------------- A stage (synth -> LDS) ----------------
        {
            float v[16];
            bool ok;
            if constexpr (MODE == 0) {
                ok = (k16 < ICD_DIM);
                if (ok) {
                    const float* ap = Af + (size_t)(m0 + rc) * ICD_DIM + k16;
#pragma unroll
                    for (int q = 0; q < 4; ++q) {
                        float4 t = *(const float4*)(ap + q * 4);
                        v[q * 4 + 0] = t.x; v[q * 4 + 1] = t.y; v[q * 4 + 2] = t.z; v[q * 4 + 3] = t.w;
                    }
                }
            } else {
                const int w = k16 / H_DIM, h0i = k16 - (k16 / H_DIM) * H_DIM;
                const int gm = m0 + rc, b = gm >> 8, tt = gm & 255;
                const int tp = tt - (W_WIN - 1) + w;
                ok = (tp >= 0);
                if (ok) {
                    const float lw = ldwp[(size_t)gm * W_WIN + w];
                    const float* ap = hall + ((size_t)(b * T_DIM + tp)) * H_DIM + h0i;
#pragma unroll
                    for (int q = 0; q < 4; ++q) {
                        float4 t = *(const float4*)(ap + q * 4);
                        v[q * 4 + 0] = t.x * lw; v[q * 4 + 1] = t.y * lw;
                        v[q * 4 + 2] = t.z * lw; v[q * 4 + 3] = t.w * lw;
                    }
                }
            }
            if (!ok) {
#pragma unroll
                for (int q = 0; q < 16; ++q) v[q] = 0.f;
            }
            uint_t hh[8];
#pragma unroll
            for (int i = 0; i < 8; ++i) {
                ushort_t h0 = f2bf(v[2 * i]), h1 = f2bf(v[2 * i + 1]);
                hh[i] = (uint_t)h0 | ((uint_t)h1 << 16);
            }
            *(uint4*)&AhS[(kq0 * 128 + rc) * 8]       = make_uint4(hh[0], hh[1], hh[2], hh[3]);
            *(uint4*)&AhS[((kq0 + 1) * 128 + rc) * 8] = make_uint4(hh[4], hh[5], hh[6], hh[7]);
        }

        // ---------------- B stage (async direct) ----------------
        {
            const ushort_t* bp = Bh + (size_t)(n0 + rc) * kdim + k16;
            GLOAD_LDS16(bp,     &BhS[(kq0 * 128 + rc) * 8]);
            GLOAD_LDS16(bp + 8, &BhS[((kq0 + 1) * 128 + rc) * 8]);
        }
        __syncthreads();

        // ---------------- MFMA ----------------
        short8 ah[4], bh[4];
#pragma unroll
        for (int mf = 0; mf < 4; ++mf)
            ah[mf] = *(const short8*)&AhS[(lkq * 128 + wm * 64 + mf * 16 + l15) * 8];
#pragma unroll
        for (int nf = 0; nf < 4; ++nf)
            bh[nf] = *(const short8*)&BhS[(lkq * 128 + wn * 64 + nf * 16 + l15) * 8];
#pragma unroll
        for (int mf = 0; mf < 4; ++mf)
#pragma unroll
            for (int nf = 0; nf < 4; ++nf)
                acc[mf][nf] = __builtin_amdgcn_mfma_f32_16x16x32_bf16(ah[mf], bh[nf], acc[mf][nf], 0, 0, 0);
    }

    // ---------------- epilogue ----------------
#pragma unroll
    for (int mf = 0; mf < 4; ++mf)
#pragma unroll
        for (int nf = 0; nf < 4; ++nf)
#pragma unroll
            for (int j = 0; j < 4; ++j) {
                const int gm = m0 + wm * 64 + mf * 16 + lkq * 4 + j;
                const int gn = n0 + wn * 64 + nf * 16 + l15;
                float v = acc[mf][nf][j] + bias[gn];
                if constexpr (MODE == 0) {
                    ushort_t h = f2bf(v);
                    Ehi[(size_t)gm * H_DIM + gn] = h;
                    Elo[(size_t)gm * H_DIM + gn] = f2bf(v - bf2f(h));
                } else {
                    const size_t ix = (size_t)gm * H_DIM + gn;
                    v = v * bf2f(theme[ix]) + hall[ix];
                    Cb[ix] = f2bf(v);
                }
            }
}

// ---------------------------------------------------------------------------
// MFMA bf16 GEMM, 256x128 tile, BK=32, 512 threads (8 waves, 4m x 2n).
// MODE 1: A = Ehi/Elo (2 passes), B = ker_hi, out Xproj f32 (+bias)
// MODE 3: A = rnnb (1 pass),      B = outw_t, out d_out f32 (+bias)
// ---------------------------------------------------------------------------
template<int MODE>
__global__ __launch_bounds__(512)
void mfma_gemm256(const ushort_t* __restrict__ Ah, const ushort_t* __restrict__ Al,
                  const ushort_t* __restrict__ Bm, float* __restrict__ Cf,
                  const float* __restrict__ bias,
                  int ksteps, int kdim, int astride, int ncols, int cld)
{
    constexpr bool SPLITA = (MODE == 1);
    __shared__ ushort_t AhS[8192];
    __shared__ ushort_t AlS[SPLITA ? 8192 : 16];
    __shared__ ushort_t BhS[4096];

    const int tid = threadIdx.x;
    const int m0 = blockIdx.y * 256, n0 = blockIdx.x * 128;

    const int arow = tid & 255, akh = tid >> 8;
    const int akq0 = akh * 2;
    const int bcol = tid & 127, bkq = tid >> 7;

    const int lane = tid & 63, wid = tid >> 6;
    const int wm = wid >> 1, wn = wid & 1;
    const int l15 = lane & 15, lkq = lane >> 4;

    f32x4 acc[4][4];
#pragma unroll
    for (int i = 0; i < 4; ++i)
#pragma unroll
        for (int j = 0; j < 4; ++j)
#pragma unroll
            for (int q = 0; q < 4; ++q) acc[i][j][q] = 0.f;

    for (int ks = 0; ks < ksteps; ++ks) {
        const int kb = ks * 32;
        __syncthreads();
        {
            const ushort_t* ap = Ah + (size_t)(m0 + arow) * astride + kb + akh * 16;
            GLOAD_LDS16(ap,     &AhS[((akq0 + 0) * 256 + arow) * 8]);
            GLOAD_LDS16(ap + 8, &AhS[((akq0 + 1) * 256 + arow) * 8]);
            if constexpr (SPLITA) {
                const ushort_t* ap2 = Al + (size_t)(m0 + arow) * astride + kb + akh * 16;
                GLOAD_LDS16(ap2,     &AlS[((akq0 + 0) * 256 + arow) * 8]);
                GLOAD_LDS16(ap2 + 8, &AlS[((akq0 + 1) * 256 + arow) * 8]);
            }
        }
        {
            const ushort_t* bp = Bm + (size_t)(n0 + bcol) * kdim + kb + bkq * 8;
            GLOAD_LDS16(bp, &BhS[(bkq * 128 + bcol) * 8]);
        }
        __syncthreads();

        short8 ah[4], al[4], bh[4];
#pragma unroll
        for (int mf = 0; mf < 4; ++mf)
            ah[mf] = *(const short8*)&AhS[(lkq * 256 + wm * 64 + mf * 16 + l15) * 8];
#pragma unroll
        for (int nf = 0; nf < 4; ++nf)
            bh[nf] = *(const short8*)&BhS[(lkq * 128 + wn * 64 + nf * 16 + l15) * 8];
        if constexpr (SPLITA) {
#pragma unroll
            for (int mf = 0; mf < 4; ++mf)
                al[mf] = *(const short8*)&AlS[(lkq * 256 + wm * 64 + mf * 16 + l15) * 8];
        }
#pragma unroll
        for (int mf = 0; mf < 4; ++mf)
#pragma unroll
            for (int nf = 0; nf < 4; ++nf) {
                acc[mf][nf] = __builtin_amdgcn_mfma_f32_16x16x32_bf16(ah[mf], bh[nf], acc[mf][nf], 0, 0, 0);
                if constexpr (SPLITA)
                    acc[mf][nf] = __builtin_amdgcn_mfma_f32_16x16x32_bf16(al[mf], bh[nf], acc[mf][nf], 0, 0, 0);
            }
    }

#pragma unroll
    for (int mf = 0; mf < 4; ++mf)
#pragma unroll
        for (int nf = 0; nf < 4; ++nf)
#pragma unroll
            for (int j = 0; j < 4; ++j) {
                const int gm = m0 + wm * 64 + mf * 16 + lkq * 4 + j;
                const int gn = n0 + wn * 64 + nf * 16 + l15;
                if (gn < ncols)
                    Cf[(size_t)gm * cld + gn] = acc[mf][nf][j] + bias[gn];
            }
}

// ---------------------------------------------------------------------------
// persistent scan: 256 blocks = 4 col-quarters x 64 batches, 768 threads.
// round-5 exchange (proven). NEW: theme/local_dis for step t-1 computed by
// wave 11 in the spin shadow (11-deep LDS h-ring); ld softmax by tid 64.
// locdis2 kernel eliminated.
// ---------------------------------------------------------------------------
__global__ __launch_bounds__(768, 3)
void scan_kernel(const float* __restrict__ Xproj, const uint_t* __restrict__ recg,
                 const uint_t* __restrict__ recm, float* __restrict__ h_all,
                 uint_t* __restrict__ hpk,
                 const uint_t* __restrict__ scale2, const uint_t* __restrict__ resc2,
                 const float* __restrict__ scale_b, const float* __restrict__ rescale_b,
                 ushort_t* __restrict__ theme, float* __restrict__ ldw)
{
    __shared__ ushort_t hs16[H_DIM];        // h_{t-1} as f16
    __shared__ ushort_t ring[11][H_DIM];    // h history (f16), depth 11
    __shared__ float xo_s[384];
    __shared__ uint_t wm2[6 * 192];
    __shared__ float c_s[96];
    __shared__ float fm_s[3], im_s[3];
    __shared__ float dis_ring[11];
    __shared__ float ld_s[10];
    __shared__ uint_t mh2[192];
    __shared__ float hid[64];
    __shared__ uint_t hid2[32];

    const int tid = threadIdx.x;
    const int q = blockIdx.x >> 6, b = blockIdx.x & 63;

    const int cg = tid >> 1, half = tid & 1;
    const int jg = 6 + (cg >> 5) * 128 + q * 32 + (cg & 31);

    const int gl = tid / 32, gu = tid & 31;
    const int jglob = gl * 128 + q * 32 + gu;

    const int rsp = tid - 96;
    const int qq_sp = (q + 1 + rsp / 96) & 3;
    const int s_sp = rsp % 96;
    const int j_sp = (s_sp >> 5) * 128 + qq_sp * 32 + (s_sp & 31);

    for (int i = tid; i < 6 * 192; i += 768) wm2[i] = recm[i];
    if (tid < H_DIM) hs16[tid] = 0;
    if (tid < 96) c_s[tid] = 0.f;

    uint_t w[96];
#pragma unroll
    for (int kk = 0; kk < 96; ++kk)
        w[kk] = recg[(size_t)((q * 2 + half) * 96 + kk) * 384 + cg];

    float xv = 0.f, xvm = 0.f;
    if (half == 0) xv = Xproj[((size_t)b * T_DIM + 0) * XO_DIM + jg];
    if (tid < 24 && (tid & 3) == 0) xvm = Xproj[((size_t)b * T_DIM + 0) * XO_DIM + (tid >> 2)];

    __syncthreads();

    for (int t = 0; t < T_DIM; ++t) {
        // ---- matvec: xo = Xproj + h @ rec_w (all 768 threads) ----
        {
            float acc = 0.f;
            const ushort_t* hp = &hs16[half * 192];
#pragma unroll
            for (int kk = 0; kk < 96; kk += 4) {
                const uint4 hq = *(const uint4*)(hp + kk * 2);
                acc = dot2f(w[kk + 0], hq.x, acc);
                acc = dot2f(w[kk + 1], hq.y, acc);
                acc = dot2f(w[kk + 2], hq.z, acc);
                acc = dot2f(w[kk + 3], hq.w, acc);
            }
            acc += __shfl_xor(acc, 1);
            if (half == 0) xo_s[cg] = acc + xv;
        }

        // ---- master cols + softmax in wave 0; dis -> dis_ring ----
        if (tid < 64) {
            float acc = 0.f;
            if (tid < 24) {
                const int mc = tid >> 2, kq = tid & 3;
                const uint_t* wp = &wm2[mc * 192 + kq * 48];
#pragma unroll
                for (int kk = 0; kk < 48; kk += 4) {
                    const uint4 hq = *(const uint4*)&hs16[(kq * 48 + kk) * 2];
                    acc = dot2f(wp[kk + 0], hq.x, acc);
                    acc = dot2f(wp[kk + 1], hq.y, acc);
                    acc = dot2f(wp[kk + 2], hq.z, acc);
                    acc = dot2f(wp[kk + 3], hq.w, acc);
                }
                if ((tid & 3) == 0) acc += xvm;
            }
            acc += __shfl_xor(acc, 2);
            acc += __shfl_xor(acc, 1);
            const float m0 = __shfl(acc, 0),  m1 = __shfl(acc, 4),  m2 = __shfl(acc, 8);
            const float m3 = __shfl(acc, 12), m4 = __shfl(acc, 16), m5 = __shfl(acc, 20);
            if (tid == 0) {
                float mx = fmaxf(m0, fmaxf(m1, m2));
                float e0 = expf(m0 - mx), e1 = expf(m1 - mx), e2 = expf(m2 - mx);
                float inv = 1.f / (e0 + e1 + e2);
                const float f0 = e0 * inv, f1 = (e0 + e1) * inv;
                fm_s[0] = f0; fm_s[1] = f1; fm_s[2] = 1.f;
                mx = fmaxf(m3, fmaxf(m4, m5));
                e0 = expf(m3 - mx); e1 = expf(m4 - mx); e2 = expf(m5 - mx);
                inv = 1.f / (e0 + e1 + e2);
                im_s[0] = 1.f; im_s[1] = (e1 + e2) * inv; im_s[2] = e2 * inv;
                dis_ring[t % 11] = 1.f - (f0 + f1 + 1.f) * (1.f / 3.f);
            }
        }
        // ---- ld softmax for t-1 (tid 64, parallel wave) ----
        if (tid == 64 && t >= 1) {
            const int tpr = t - 1;
            float cum = 0.f, c[10];
            for (int wq = 0; wq < 10; ++wq) {
                const int tp = tpr - 9 + wq;
                cum += (tp >= 0) ? dis_ring[tp % 11] : 0.f;
                c[wq] = cum;
            }
            float mx = c[0];
            for (int wq = 1; wq < 10; ++wq) mx = fmaxf(mx, c[wq]);
            float s = 0.f, e[10];
            for (int wq = 0; wq < 10; ++wq) { e[wq] = expf(c[wq] - mx); s += e[wq]; }
            const float inv = 1.f / s;
            for (int wq = 0; wq < 10; ++wq) {
                ld_s[wq] = e[wq] * inv;
                if (q == 0) ldw[((size_t)b * T_DIM + tpr) * W_WIN + wq] = e[wq] * inv;
            }
        }
        __syncthreads();

        // ---- gates / cell update + publish own 96 h-elements ----
        if (tid < 96) {
            const float fm = fm_s[gl], im = im_s[gl];
            const float fg = sigmoidf_(xo_s[gl * 32 + gu]);
            const float ig = sigmoidf_(xo_s[(3 + gl) * 32 + gu]);
            const float og = sigmoidf_(xo_s[(6 + gl) * 32 + gu]);
            const float ci = tanhf(xo_s[(9 + gl) * 32 + gu]);
            const float cl = c_s[tid];
            const float ov = fm * im;
            const float cn = ov * (fg * cl + ig * ci) + (fm - ov) * cl + (im - ov) * ci;
            const float hn = og * tanhf(cn);
            _Float16 hf = (_Float16)hn;
            ushort_t hb; __builtin_memcpy(&hb, &hf, 2);
            const uint_t word = ((uint_t)hb << 16) | (uint_t)(t + 1);
            __hip_atomic_store(&hpk[(size_t)(t & 1) * B_DIM * H_DIM + b * H_DIM + jglob],
                               word, __ATOMIC_RELAXED, __HIP_MEMORY_SCOPE_AGENT);
            c_s[tid] = cn;
            hs16[jglob] = hb;
            ring[t % 11][jglob] = hb;
            h_all[((size_t)b * T_DIM + t) * H_DIM + jglob] = hn;
        }

        // ---- prefetch next Xproj ----
        if (t + 1 < T_DIM) {
            if (half == 0) xv = Xproj[((size_t)b * T_DIM + (t + 1)) * XO_DIM + jg];
            if (tid < 24 && (tid & 3) == 0) xvm = Xproj[((size_t)b * T_DIM + (t + 1)) * XO_DIM + (tid >> 2)];
        }

        // ---- THEME for t-1 (wave 11, in spin shadow) ----
        if (tid >= 704 && t >= 1) {
            const int tpr = t - 1;
            const int ln = tid - 704;
#pragma unroll
            for (int pp = 0; pp < 3; ++pp) {
                const int p = ln * 3 + pp;
                float a0 = 0.f, a1 = 0.f;
                for (int wq = 0; wq < 10; ++wq) {
                    const int tp = tpr - 9 + wq;
                    if (tp >= 0) {
                        const float lw = ld_s[wq];
                        const int r = tp % 11;
                        _Float16 h0, h1;
                        __builtin_memcpy(&h0, &ring[r][2 * p], 2);
                        __builtin_memcpy(&h1, &ring[r][2 * p + 1], 2);
                        a0 += lw * (float)h0; a1 += lw * (float)h1;
                    }
                }
                mh2[p] = pkf16(a0 * 0.1f, a1 * 0.1f);
            }
            asm volatile("s_waitcnt lgkmcnt(0)" ::: "memory");
            __builtin_amdgcn_sched_barrier(0);
            {
                float acc = 0.f;
#pragma unroll 8
                for (int k = 0; k < 192; ++k)
                    acc = dot2f(scale2[k * 64 + ln], mh2[k], acc);
                hid[ln] = fmaxf(acc + scale_b[ln], 0.f);
            }
            asm volatile("s_waitcnt lgkmcnt(0)" ::: "memory");
            __builtin_amdgcn_sched_barrier(0);
            if (ln < 32) hid2[ln] = pkf16(hid[2 * ln], hid[2 * ln + 1]);
            asm volatile("s_waitcnt lgkmcnt(0)" ::: "memory");
            __builtin_amdgcn_sched_barrier(0);
#pragma unroll
            for (int rep = 0; rep < 2; ++rep) {
                const int s = rep * 64 + ln;
                if (s < 96) {
                    const int j2 = (s >> 5) * 128 + q * 32 + (s & 31);
                    float acc = 0.f;
#pragma unroll
                    for (int k = 0; k < 32; ++k)
                        acc = dot2f(resc2[k * 384 + j2], hid2[k], acc);
                    theme[((size_t)b * T_DIM + tpr) * H_DIM + j2] = f2bf(sigmoidf_(acc + rescale_b[j2]));
                }
            }
        }

        // ---- consume 288 foreign h words (exact-tag spin, agent scope) ----
        if (tid >= 96 && tid < 384) {
            const uint_t want = (uint_t)(t + 1);
            uint_t* addr = &hpk[(size_t)(t & 1) * B_DIM * H_DIM + b * H_DIM + j_sp];
            uint_t v = __hip_atomic_load(addr, __ATOMIC_RELAXED, __HIP_MEMORY_SCOPE_AGENT);
            while ((v & 0xFFFFu) != want) {
                __builtin_amdgcn_s_sleep(1);
                v = __hip_atomic_load(addr, __ATOMIC_RELAXED, __HIP_MEMORY_SCOPE_AGENT);
            }
            hs16[j_sp] = (ushort_t)(v >> 16);
            ring[t % 11][j_sp] = (ushort_t)(v >> 16);
        }
        __syncthreads();
    }

    // ---- tail: theme for t = 255 (wave 11 only) ----
    if (tid >= 704) {
        const int tpr = T_DIM - 1;
        const int ln = tid - 704;
        if (ln == 0) {
            float cum = 0.f, c[10];
            for (int wq = 0; wq < 10; ++wq) {
                const int tp = tpr - 9 + wq;
                cum += (tp >= 0) ? dis_ring[tp % 11] : 0.f;
                c[wq] = cum;
            }
            float mx = c[0];
            for (int wq = 1; wq < 10; ++wq) mx = fmaxf(mx, c[wq]);
            float s = 0.f, e[10];
            for (int wq = 0; wq < 10; ++wq) { e[wq] = expf(c[wq] - mx); s += e[wq]; }
            const float inv = 1.f / s;
            for (int wq = 0; wq < 10; ++wq) {
                ld_s[wq] = e[wq] * inv;
                if (q == 0) ldw[((size_t)b * T_DIM + tpr) * W_WIN + wq] = e[wq] * inv;
            }
        }
        asm volatile("s_waitcnt lgkmcnt(0)" ::: "memory");
        __builtin_amdgcn_sched_barrier(0);
#pragma unroll
        for (int pp = 0; pp < 3; ++pp) {
            const int p = ln * 3 + pp;
            float a0 = 0.f, a1 = 0.f;
            for (int wq = 0; wq < 10; ++wq) {
                const int tp = tpr - 9 + wq;
                if (tp >= 0) {
                    const float lw = ld_s[wq];
                    const int r = tp % 11;
                    _Float16 h0, h1;
                    __builtin_memcpy(&h0, &ring[r][2 * p], 2);
                    __builtin_memcpy(&h1, &ring[r][2 * p + 1], 2);
                    a0 += lw * (float)h0; a1 += lw * (float)h1;
                }
            }
            mh2[p] = pkf16(a0 * 0.1f, a1 * 0.1f);
        }
        asm volatile("s_waitcnt lgkmcnt(0)" ::: "memory");
        __builtin_amdgcn_sched_barrier(0);
        {
            float acc = 0.f;
#pragma unroll 8
            for (int k = 0; k < 192; ++k)
                acc = dot2f(scale2[k * 64 + ln], mh2[k], acc);
            hid[ln] = fmaxf(acc + scale_b[ln], 0.f);
        }
        asm volatile("s_waitcnt lgkmcnt(0)" ::: "memory");
        __builtin_amdgcn_sched_barrier(0);
        if (ln < 32) hid2[ln] = pkf16(hid[2 * ln], hid[2 * ln + 1]);
        asm volatile("s_waitcnt lgkmcnt(0)" ::: "memory");
        __builtin_amdgcn_sched_barrier(0);
#pragma unroll
        for (int rep = 0; rep < 2; ++rep) {
            const int s = rep * 64 + ln;
            if (s < 96) {
                const int j2 = (s >> 5) * 128 + q * 32 + (s & 31);
                float acc = 0.f;
#pragma unroll
                for (int k = 0; k < 32; ++k)
                    acc = dot2f(resc2[k * 384 + j2], hid2[k], acc);
                theme[((size_t)b * T_DIM + tpr) * H_DIM + j2] = f2bf(sigmoidf_(acc + rescale_b[j2]));
            }
        }
    }
}

// ---------------------------------------------------------------------------
extern "C" void kernel_launch(void* const* d_in, const int* in_sizes, int n_in,
                              void* d_out, int out_size, void* d_ws, size_t ws_size,
                              hipStream_t stream)
{
    const float* x         = (const float*)d_in[0];
    const float* dia_w     = (const float*)d_in[1];
    const float* dia_b     = (const float*)d_in[2];
    const float* kernel_w  = (const float*)d_in[3];
    const float* kernel_b  = (const float*)d_in[4];
    const float* rec_w     = (const float*)d_in[5];
    const float* rec_b     = (const float*)d_in[6];
    const float* scale_w   = (const float*)d_in[7];
    const float* scale_b   = (const float*)d_in[8];
    const float* rescale_w = (const float*)d_in[9];
    const float* rescale_b = (const float*)d_in[10];
    const float* conv_w    = (const float*)d_in[11];
    const float* conv_b    = (const float*)d_in[12];
    const float* out_w     = (const float*)d_in[13];
    const float* out_b     = (const float*)d_in[14];
    (void)in_sizes; (void)n_in; (void)out_size; (void)ws_size;

    float* ws = (float*)d_ws;
    size_t off = 0;
    float* Xproj   = ws + off; off += (size_t)M_DIM * XO_DIM;
    float* h_all   = ws + off; off += (size_t)M_DIM * H_DIM;
    float* ldw     = ws + off; off += (size_t)M_DIM * W_WIN;
    float* bias2p  = ws + off; off += XO_PAD;
    float* outbp   = ws + off; off += N_OUTP;
    uint_t* hpk    = (uint_t*)(ws + off); off += (size_t)2 * B_DIM * H_DIM;
    uint_t* scale2 = (uint_t*)(ws + off); off += 192 * 64;
    uint_t* resc2  = (uint_t*)(ws + off); off += 32 * 384;
    ushort_t* us = (ushort_t*)(ws + off);
    size_t uo = 0;
    ushort_t* dia_hi = us + uo; uo += (size_t)H_DIM * K_X;
    ushort_t* ker_hi = us + uo; uo += (size_t)XO_PAD * H_DIM;
    ushort_t* conv_t = us + uo; uo += (size_t)H_DIM * KCONV;
    ushort_t* outw_t = us + uo; uo += (size_t)N_OUTP * H_DIM;
    ushort_t* ehi    = us + uo; uo += (size_t)M_DIM * H_DIM;
    ushort_t* elo    = us + uo; uo += (size_t)M_DIM * H_DIM;
    ushort_t* themeb = us + uo; uo += (size_t)M_DIM * H_DIM;
    ushort_t* rnnb   = us + uo; uo += (size_t)M_DIM * H_DIM;
    uint_t* recg = (uint_t*)(us + uo); uo += (size_t)2 * 4 * 2 * 96 * 384;
    uint_t* recm = (uint_t*)(us + uo); uo += (size_t)2 * 6 * 192;

    // --- prep ---
    prep_dia <<<(H_DIM * K_X + 255) / 256, 256, 0, stream>>>(dia_w, dia_hi);
    prep_ker <<<(XO_PAD * H_DIM + 255) / 256, 256, 0, stream>>>(kernel_w, ker_hi);
    prep_conv<<<(H_DIM * KCONV + 255) / 256, 256, 0, stream>>>(conv_w, conv_t);
    prep_out <<<(N_OUTP * H_DIM + 255) / 256, 256, 0, stream>>>(out_w, outw_t);
    prep_misc<<<(N_OUTP + 255) / 256, 256, 0, stream>>>(kernel_w, kernel_b, rec_w, rec_b, out_b, bias2p, outbp);
    prep_rec2<<<(4 * 2 * 96 * 384 + 6 * 192 + 255) / 256, 256, 0, stream>>>(rec_w, recg, recm);
    prep_sr  <<<(192 * 64 + 32 * 384 + 255) / 256, 256, 0, stream>>>(scale_w, rescale_w, scale2, resc2);

    // --- embed = x @ dia_w + dia_b  (1 pass, Ehi/Elo output split) ---
    mfma_gemm<0><<<dim3(3, 128), 256, 0, stream>>>(
        x, dia_hi, nullptr, ehi, elo,
        dia_b, nullptr, nullptr, nullptr, K_X / 32, K_X);

    // --- Xproj = embed @ kernel_w + bias2  (256-tile, A hi/lo 2 passes) ---
    mfma_gemm256<1><<<dim3(13, 64), 512, 0, stream>>>(
        ehi, elo, ker_hi, Xproj, bias2p, H_DIM / 32, H_DIM, H_DIM, XO_DIM, XO_DIM);

    // --- persistent recurrence + fused theme/local_dis (cooperative) ---
    {
        void* args[] = { (void*)&Xproj, (void*)&recg, (void*)&recm,
                         (void*)&h_all, (void*)&hpk,
                         (void*)&scale2, (void*)&resc2,
                         (void*)&scale_b, (void*)&rescale_b,
                         (void*)&themeb, (void*)&ldw };
        (void)hipLaunchCooperativeKernel((const void*)scan_kernel, dim3(256), dim3(768), args, 0, stream);
    }

    // --- rnn_bf = bf16( (local_h . conv_w + conv_b) * theme + h_all ) ---
    mfma_gemm<2><<<dim3(3, 128), 256, 0, stream>>>(
        nullptr, conv_t, rnnb, nullptr, nullptr,
        conv_b, themeb, h_all, ldw, KCONV / 32, KCONV);

    // --- out = rnn @ out_w + out_b  (256-tile) ---
    mfma_gemm256<3><<<dim3(16, 64), 512, 0, stream>>>(
        rnnb, nullptr, outw_t, (float*)d_out, outbp, H_DIM / 32, H_DIM, H_DIM, ICD_DIM, ICD_DIM);
}

// Round 11
// 1355.962 us; speedup vs baseline: 6.3426x; 6.3426x over previous
//
#include <hip/hip_runtime.h>
#include <hip/hip_bf16.h>
#include <cstdint>
#include <cstddef>

#define B_DIM   64
#define T_DIM   256
#define ICD_DIM 2000
#define H_DIM   384
#define CH_DIM  128
#define W_WIN   10
#define M_DIM   (B_DIM * T_DIM)         // 16384
#define XO_DIM  1542                    // 4H + 2L
#define XO_PAD  1664                    // 13*128
#define K_X     2016                    // 2000 padded to 63*32
#define KCONV   3840                    // H*W
#define N_OUTP  2048                    // 2000 padded to 16*128

typedef unsigned short ushort_t;
typedef unsigned int   uint_t;
typedef __attribute__((ext_vector_type(8))) short short8;
typedef __attribute__((ext_vector_type(4))) float f32x4;
typedef __attribute__((ext_vector_type(2))) _Float16 f16x2;

__device__ __forceinline__ ushort_t f2bf(float v) {
    __hip_bfloat16 b = __float2bfloat16(v);
    ushort_t u; __builtin_memcpy(&u, &b, 2); return u;
}
__device__ __forceinline__ float bf2f(ushort_t u) {
    __hip_bfloat16 b; __builtin_memcpy(&b, &u, 2); return __bfloat162float(b);
}
__device__ __forceinline__ uint_t pk2bf(float a, float b) {
    return (uint_t)f2bf(a) | ((uint_t)f2bf(b) << 16);
}
__device__ __forceinline__ float sigmoidf_(float x) { return 1.f / (1.f + expf(-x)); }
__device__ __forceinline__ f16x2 asf16x2(uint_t u) { f16x2 h; __builtin_memcpy(&h, &u, 4); return h; }
__device__ __forceinline__ uint_t pkf16(float a, float b) {
    f16x2 h; h.x = (_Float16)a; h.y = (_Float16)b;
    uint_t u; __builtin_memcpy(&u, &h, 4); return u;
}
__device__ __forceinline__ float dot2f(uint_t a, uint_t b, float acc) {
#if __has_builtin(__builtin_amdgcn_fdot2)
    return __builtin_amdgcn_fdot2(asf16x2(a), asf16x2(b), acc, false);
#else
    f16x2 ha = asf16x2(a), hb = asf16x2(b);
    return acc + (float)ha.x * (float)hb.x + (float)ha.y * (float)hb.y;
#endif
}

// async global -> LDS, 16 bytes per lane (wave-uniform base + lane*16)
#define GLOAD_LDS16(g, l) __builtin_amdgcn_global_load_lds( \
    (const __attribute__((address_space(1))) void*)(g),     \
    (__attribute__((address_space(3))) void*)(l), 16, 0, 0)

// ---------------------------------------------------------------------------
// prep kernels
// ---------------------------------------------------------------------------
// x (f32, [M][2000]) -> xb (bf16, [M][2016], zero-padded)
__global__ void prep_x(const float* __restrict__ x, ushort_t* __restrict__ xb)
{
    int id = blockIdx.x * 256 + threadIdx.x;
    if (id >= M_DIM * (K_X / 8)) return;
    const int m = id / (K_X / 8), c = id - m * (K_X / 8);
    const int k = c * 8;
    uint_t o[4];
    if (k + 7 < ICD_DIM) {
        const float* p = x + (size_t)m * ICD_DIM + k;
        const float4 a = *(const float4*)p;
        const float4 b = *(const float4*)(p + 4);
        o[0] = pk2bf(a.x, a.y); o[1] = pk2bf(a.z, a.w);
        o[2] = pk2bf(b.x, b.y); o[3] = pk2bf(b.z, b.w);
    } else {
        float v[8];
#pragma unroll
        for (int i = 0; i < 8; ++i)
            v[i] = (k + i < ICD_DIM) ? x[(size_t)m * ICD_DIM + k + i] : 0.f;
        o[0] = pk2bf(v[0], v[1]); o[1] = pk2bf(v[2], v[3]);
        o[2] = pk2bf(v[4], v[5]); o[3] = pk2bf(v[6], v[7]);
    }
    *(uint4*)&xb[(size_t)m * K_X + k] = make_uint4(o[0], o[1], o[2], o[3]);
}
__global__ void prep_dia(const float* __restrict__ dia_w, ushort_t* __restrict__ hi)
{
    int id = blockIdx.x * 256 + threadIdx.x;
    if (id >= H_DIM * K_X) return;
    int n = id / K_X, k = id - n * K_X;
    hi[id] = f2bf((k < ICD_DIM) ? dia_w[(size_t)k * H_DIM + n] : 0.f);
}
__global__ void prep_ker(const float* __restrict__ kernel_w, ushort_t* __restrict__ hi)
{
    int id = blockIdx.x * 256 + threadIdx.x;
    if (id >= XO_PAD * H_DIM) return;
    int n = id / H_DIM, k = id - n * H_DIM;
    hi[id] = f2bf((n < XO_DIM) ? kernel_w[(size_t)k * XO_DIM + n] : 0.f);
}
__global__ void prep_conv(const float* __restrict__ conv_w, ushort_t* __restrict__ bt)
{
    int id = blockIdx.x * 256 + threadIdx.x;
    if (id >= H_DIM * KCONV) return;
    int o = id / KCONV, k = id - o * KCONV;
    int w = k / H_DIM, h = k - w * H_DIM;
    bt[id] = f2bf(conv_w[((size_t)o * H_DIM + h) * W_WIN + w]);
}
__global__ void prep_out(const float* __restrict__ out_w, ushort_t* __restrict__ bt)
{
    int id = blockIdx.x * 256 + threadIdx.x;
    if (id >= N_OUTP * H_DIM) return;
    int n = id / H_DIM, k = id - n * H_DIM;
    bt[id] = f2bf((n < ICD_DIM) ? out_w[(size_t)k * ICD_DIM + n] : 0.f);
}
__global__ void prep_misc(const float* __restrict__ kernel_w, const float* __restrict__ kernel_b,
                          const float* __restrict__ rec_w, const float* __restrict__ rec_b,
                          const float* __restrict__ out_b,
                          float* __restrict__ bias2p, float* __restrict__ outbp)
{
    int j = blockIdx.x * 256 + threadIdx.x;
    if (j < XO_PAD)
        bias2p[j] = (j < XO_DIM) ? (kernel_w[(size_t)H_DIM * XO_DIM + j] + kernel_b[j]
                                  + rec_w[(size_t)H_DIM * XO_DIM + j] + rec_b[j]) : 0.f;
    if (j < N_OUTP)
        outbp[j] = (j < ICD_DIM) ? out_b[j] : 0.f;
}
// rec_w gate cols -> recg[((q*2+half)*96 + kk)*384 + cg]; master cols -> recm[mc*192 + p]
__global__ void prep_rec2(const float* __restrict__ rec_w, uint_t* __restrict__ recg, uint_t* __restrict__ recm)
{
    int id = blockIdx.x * 256 + threadIdx.x;
    const int NG = 4 * 2 * 96 * 384;
    if (id < NG) {
        int cg = id % 384;
        int kk = (id / 384) % 96;
        int half = (id / (384 * 96)) & 1;
        int q = id / (384 * 96 * 2);
        int p = half * 96 + kk;
        int j = 6 + (cg >> 5) * 128 + q * 32 + (cg & 31);
        recg[id] = pkf16(rec_w[(size_t)(2 * p) * XO_DIM + j], rec_w[(size_t)(2 * p + 1) * XO_DIM + j]);
    } else if (id < NG + 6 * 192) {
        int id2 = id - NG;
        int mc = id2 / 192, p = id2 % 192;
        recm[id2] = pkf16(rec_w[(size_t)(2 * p) * XO_DIM + mc], rec_w[(size_t)(2 * p + 1) * XO_DIM + mc]);
    }
}

// ---------------------------------------------------------------------------
// MFMA bf16 GEMM, 128x128 tile, BK=32, 256 threads.
// MODE 0: A = xb (bf16, direct gload_lds), B = dia_hi, out Ehi/Elo split
// MODE 2: A = local_h synth, B = convT, fused theme epilogue
// ---------------------------------------------------------------------------
template<int MODE>
__global__ __launch_bounds__(256)
void mfma_gemm(const ushort_t* __restrict__ Ab,
               const ushort_t* __restrict__ Bh,
               ushort_t* __restrict__ Cb,
               ushort_t* __restrict__ Ehi, ushort_t* __restrict__ Elo,
               const float* __restrict__ bias,
               const ushort_t* __restrict__ theme,
               const float* __restrict__ hall, const float* __restrict__ ldwp,
               int ksteps, int kdim, int astride)
{
    __shared__ ushort_t AhS[4096];
    __shared__ ushort_t BhS[4096];

    const int tid = threadIdx.x;
    const int rc = tid & 127, kh = tid >> 7;
    const int m0 = blockIdx.y * 128, n0 = blockIdx.x * 128;
    const int kq0 = kh * 2;

    const int lane = tid & 63, wid = tid >> 6;
    const int wm = wid >> 1, wn = wid & 1;
    const int l15 = lane & 15, lkq = lane >> 4;

    f32x4 acc[4][4];
#pragma unroll
    for (int i = 0; i < 4; ++i)
#pragma unroll
        for (int j = 0; j < 4; ++j)
#pragma unroll
            for (int q = 0; q < 4; ++q) acc[i][j][q] = 0.f;

    for (int ks = 0; ks < ksteps; ++ks) {
        const int k16 = ks * 32 + kh * 16;
        __syncthreads();

        // ---------------- A stage ----------------
        if constexpr (MODE == 0) {
            const ushort_t* ap = Ab + (size_t)(m0 + rc) * astride + k16;
            GLOAD_LDS16(ap,     &AhS[(kq0 * 128 + rc) * 8]);
            GLOAD_LDS16(ap + 8, &AhS[((kq0 + 1) * 128 + rc) * 8]);
        } else {
            float v[16];
            const int w = k16 / H_DIM, h0i = k16 - (k16 / H_DIM) * H_DIM;
            const int gm = m0 + rc, b = gm >> 8, tt = gm & 255;
            const int tp = tt - (W_WIN - 1) + w;
            const bool ok = (tp >= 0);
            if (ok) {
                const float lw = ldwp[(size_t)gm * W_WIN + w];
                const float* ap = hall + ((size_t)(b * T_DIM + tp)) * H_DIM + h0i;
#pragma unroll
                for (int q = 0; q < 4; ++q) {
                    float4 t = *(const float4*)(ap + q * 4);
                    v[q * 4 + 0] = t.x * lw; v[q * 4 + 1] = t.y * lw;
                    v[q * 4 + 2] = t.z * lw; v[q * 4 + 3] = t.w * lw;
                }
            } else {
#pragma unroll
                for (int q = 0; q < 16; ++q) v[q] = 0.f;
            }
            uint_t hh[8];
#pragma unroll
            for (int i = 0; i < 8; ++i)
                hh[i] = pk2bf(v[2 * i], v[2 * i + 1]);
            *(uint4*)&AhS[(kq0 * 128 + rc) * 8]       = make_uint4(hh[0], hh[1], hh[2], hh[3]);
            *(uint4*)&AhS[((kq0 + 1) * 128 + rc) * 8] = make_uint4(hh[4], hh[5], hh[6], hh[7]);
        }

        // ---------------- B stage (async direct) ----------------
        {
            const ushort_t* bp = Bh + (size_t)(n0 + rc) * kdim + k16;
            GLOAD_LDS16(bp,     &BhS[(kq0 * 128 + rc) * 8]);
            GLOAD_LDS16(bp + 8, &BhS[((kq0 + 1) * 128 + rc) * 8]);
        }
        __syncthreads();

        // ---------------- MFMA ----------------
        short8 ah[4], bh[4];
#pragma unroll
        for (int mf = 0; mf < 4; ++mf)
            ah[mf] = *(const short8*)&AhS[(lkq * 128 + wm * 64 + mf * 16 + l15) * 8];
#pragma unroll
        for (int nf = 0; nf < 4; ++nf)
            bh[nf] = *(const short8*)&BhS[(lkq * 128 + wn * 64 + nf * 16 + l15) * 8];
#pragma unroll
        for (int mf = 0; mf < 4; ++mf)
#pragma unroll
            for (int nf = 0; nf < 4; ++nf)
                acc[mf][nf] = __builtin_amdgcn_mfma_f32_16x16x32_bf16(ah[mf], bh[nf], acc[mf][nf], 0, 0, 0);
    }

    // ---------------- epilogue ----------------
#pragma unroll
    for (int mf = 0; mf < 4; ++mf)
#pragma unroll
        for (int nf = 0; nf < 4; ++nf)
#pragma unroll
            for (int j = 0; j < 4; ++j) {
                const int gm = m0 + wm * 64 + mf * 16 + lkq * 4 + j;
                const int gn = n0 + wn * 64 + nf * 16 + l15;
                float v = acc[mf][nf][j] + bias[gn];
                if constexpr (MODE == 0) {
                    ushort_t h = f2bf(v);
                    Ehi[(size_t)gm * H_DIM + gn] = h;
                    Elo[(size_t)gm * H_DIM + gn] = f2bf(v - bf2f(h));
                } else {
                    const size_t ix = (size_t)gm * H_DIM + gn;
                    v = v * bf2f(theme[ix]) + hall[ix];
                    Cb[ix] = f2bf(v);
                }
            }
}

// ---------------------------------------------------------------------------
// MFMA bf16 GEMM, 256x128 tile, BK=32, 512 threads (8 waves, 4m x 2n).
// MODE 1: A = Ehi/Elo (2 passes), B = ker_hi, out Xproj f32 (+bias)
// MODE 3: A = rnnb (1 pass),      B = outw_t, out d_out f32 (+bias)
// ---------------------------------------------------------------------------
template<int MODE>
__global__ __launch_bounds__(512)
void mfma_gemm256(const ushort_t* __restrict__ Ah, const ushort_t* __restrict__ Al,
                  const ushort_t* __restrict__ Bm, float* __restrict__ Cf,
                  const float* __restrict__ bias,
                  int ksteps, int kdim, int astride, int ncols, int cld)
{
    constexpr bool SPLITA = (MODE == 1);
    __shared__ ushort_t AhS[8192];
    __shared__ ushort_t AlS[SPLITA ? 8192 : 16];
    __shared__ ushort_t BhS[4096];

    const int tid = threadIdx.x;
    const int m0 = blockIdx.y * 256, n0 = blockIdx.x * 128;

    const int arow = tid & 255, akh = tid >> 8;
    const int akq0 = akh * 2;
    const int bcol = tid & 127, bkq = tid >> 7;

    const int lane = tid & 63, wid = tid >> 6;
    const int wm = wid >> 1, wn = wid & 1;
    const int l15 = lane & 15, lkq = lane >> 4;

    f32x4 acc[4][4];
#pragma unroll
    for (int i = 0; i < 4; ++i)
#pragma unroll
        for (int j = 0; j < 4; ++j)
#pragma unroll
            for (int q = 0; q < 4; ++q) acc[i][j][q] = 0.f;

    for (int ks = 0; ks < ksteps; ++ks) {
        const int kb = ks * 32;
        __syncthreads();
        {
            const ushort_t* ap = Ah + (size_t)(m0 + arow) * astride + kb + akh * 16;
            GLOAD_LDS16(ap,     &AhS[((akq0 + 0) * 256 + arow) * 8]);
            GLOAD_LDS16(ap + 8, &AhS[((akq0 + 1) * 256 + arow) * 8]);
            if constexpr (SPLITA) {
                const ushort_t* ap2 = Al + (size_t)(m0 + arow) * astride + kb + akh * 16;
                GLOAD_LDS16(ap2,     &AlS[((akq0 + 0) * 256 + arow) * 8]);
                GLOAD_LDS16(ap2 + 8, &AlS[((akq0 + 1) * 256 + arow) * 8]);
            }
        }
        {
            const ushort_t* bp = Bm + (size_t)(n0 + bcol) * kdim + kb + bkq * 8;
            GLOAD_LDS16(bp, &BhS[(bkq * 128 + bcol) * 8]);
        }
        __syncthreads();

        short8 ah[4], al[4], bh[4];
#pragma unroll
        for (int mf = 0; mf < 4; ++mf)
            ah[mf] = *(const short8*)&AhS[(lkq * 256 + wm * 64 + mf * 16 + l15) * 8];
#pragma unroll
        for (int nf = 0; nf < 4; ++nf)
            bh[nf] = *(const short8*)&BhS[(lkq * 128 + wn * 64 + nf * 16 + l15) * 8];
        if constexpr (SPLITA) {
#pragma unroll
            for (int mf = 0; mf < 4; ++mf)
                al[mf] = *(const short8*)&AlS[(lkq * 256 + wm * 64 + mf * 16 + l15) * 8];
        }
#pragma unroll
        for (int mf = 0; mf < 4; ++mf)
#pragma unroll
            for (int nf = 0; nf < 4; ++nf) {
                acc[mf][nf] = __builtin_amdgcn_mfma_f32_16x16x32_bf16(ah[mf], bh[nf], acc[mf][nf], 0, 0, 0);
                if constexpr (SPLITA)
                    acc[mf][nf] = __builtin_amdgcn_mfma_f32_16x16x32_bf16(al[mf], bh[nf], acc[mf][nf], 0, 0, 0);
            }
    }

#pragma unroll
    for (int mf = 0; mf < 4; ++mf)
#pragma unroll
        for (int nf = 0; nf < 4; ++nf)
#pragma unroll
            for (int j = 0; j < 4; ++j) {
                const int gm = m0 + wm * 64 + mf * 16 + lkq * 4 + j;
                const int gn = n0 + wn * 64 + nf * 16 + l15;
                if (gn < ncols)
                    Cf[(size_t)gm * cld + gn] = acc[mf][nf][j] + bias[gn];
            }
}

// ---------------------------------------------------------------------------
// persistent scan: 256 blocks = 4 col-quarters x 64 batches, 768 threads.
// round-5 exchange protocol (proven): tag-packed f16 words, relaxed
// agent-scope atomics both sides, exact-tag spin. publish-first ordering.
// ---------------------------------------------------------------------------
__global__ __launch_bounds__(768, 3)
void scan_kernel(const float* __restrict__ Xproj, const uint_t* __restrict__ recg,
                 const uint_t* __restrict__ recm, float* __restrict__ h_all,
                 float* __restrict__ dis_all, uint_t* __restrict__ hpk)
{
    __shared__ ushort_t hs16[H_DIM];        // h_{t-1} as f16
    __shared__ float xo_s[384];             // gate cols (local index)
    __shared__ uint_t wm2[6 * 192];         // master weights (f16 pairs)
    __shared__ float c_s[96];
    __shared__ float fm_s[3], im_s[3];

    const int tid = threadIdx.x;
    const int q = blockIdx.x >> 6, b = blockIdx.x & 63;

    const int cg = tid >> 1, half = tid & 1;
    const int jg = 6 + (cg >> 5) * 128 + q * 32 + (cg & 31);

    const int gl = tid / 32, gu = tid & 31;
    const int jglob = gl * 128 + q * 32 + gu;

    const int rsp = tid - 96;
    const int qq_sp = (q + 1 + rsp / 96) & 3;
    const int s_sp = rsp % 96;
    const int j_sp = (s_sp >> 5) * 128 + qq_sp * 32 + (s_sp & 31);

    for (int i = tid; i < 6 * 192; i += 768) wm2[i] = recm[i];
    if (tid < H_DIM) hs16[tid] = 0;
    if (tid < 96) c_s[tid] = 0.f;

    uint_t w[96];
#pragma unroll
    for (int kk = 0; kk < 96; ++kk)
        w[kk] = recg[(size_t)((q * 2 + half) * 96 + kk) * 384 + cg];

    float xv = 0.f, xvm = 0.f;
    if (half == 0) xv = Xproj[((size_t)b * T_DIM + 0) * XO_DIM + jg];
    if (tid < 24 && (tid & 3) == 0) xvm = Xproj[((size_t)b * T_DIM + 0) * XO_DIM + (tid >> 2)];

    __syncthreads();

    for (int t = 0; t < T_DIM; ++t) {
        // ---- matvec: xo = Xproj + h @ rec_w (all 768 threads) ----
        {
            float acc = 0.f;
            const ushort_t* hp = &hs16[half * 192];
#pragma unroll
            for (int kk = 0; kk < 96; kk += 4) {
                const uint4 hq = *(const uint4*)(hp + kk * 2);
                acc = dot2f(w[kk + 0], hq.x, acc);
                acc = dot2f(w[kk + 1], hq.y, acc);
                acc = dot2f(w[kk + 2], hq.z, acc);
                acc = dot2f(w[kk + 3], hq.w, acc);
            }
            acc += __shfl_xor(acc, 1);
            if (half == 0) xo_s[cg] = acc + xv;
        }

        // ---- master cols + softmax, fully inside wave 0 ----
        if (tid < 64) {
            float acc = 0.f;
            if (tid < 24) {
                const int mc = tid >> 2, kq = tid & 3;
                const uint_t* wp = &wm2[mc * 192 + kq * 48];
#pragma unroll
                for (int kk = 0; kk < 48; kk += 4) {
                    const uint4 hq = *(const uint4*)&hs16[(kq * 48 + kk) * 2];
                    acc = dot2f(wp[kk + 0], hq.x, acc);
                    acc = dot2f(wp[kk + 1], hq.y, acc);
                    acc = dot2f(wp[kk + 2], hq.z, acc);
                    acc = dot2f(wp[kk + 3], hq.w, acc);
                }
                if ((tid & 3) == 0) acc += xvm;
            }
            acc += __shfl_xor(acc, 2);
            acc += __shfl_xor(acc, 1);
            const float m0 = __shfl(acc, 0),  m1 = __shfl(acc, 4),  m2 = __shfl(acc, 8);
            const float m3 = __shfl(acc, 12), m4 = __shfl(acc, 16), m5 = __shfl(acc, 20);
            if (tid == 0) {
                float mx = fmaxf(m0, fmaxf(m1, m2));
                float e0 = expf(m0 - mx), e1 = expf(m1 - mx), e2 = expf(m2 - mx);
                float inv = 1.f / (e0 + e1 + e2);
                const float f0 = e0 * inv, f1 = (e0 + e1) * inv;
                fm_s[0] = f0; fm_s[1] = f1; fm_s[2] = 1.f;
                mx = fmaxf(m3, fmaxf(m4, m5));
                e0 = expf(m3 - mx); e1 = expf(m4 - mx); e2 = expf(m5 - mx);
                inv = 1.f / (e0 + e1 + e2);
                im_s[0] = 1.f; im_s[1] = (e1 + e2) * inv; im_s[2] = e2 * inv;
                if (q == 0)
                    dis_all[b * T_DIM + t] = 1.f - (f0 + f1 + 1.f) * (1.f / 3.f);
            }
        }
        __syncthreads();

        // ---- gates / cell update + publish own 96 h-elements ----
        if (tid < 96) {
            const float fm = fm_s[gl], im = im_s[gl];
            const float fg = sigmoidf_(xo_s[gl * 32 + gu]);
            const float ig = sigmoidf_(xo_s[(3 + gl) * 32 + gu]);
            const float og = sigmoidf_(xo_s[(6 + gl) * 32 + gu]);
            const float ci = tanhf(xo_s[(9 + gl) * 32 + gu]);
            const float cl = c_s[tid];
            const float ov = fm * im;
            const float cn = ov * (fg * cl + ig * ci) + (fm - ov) * cl + (im - ov) * ci;
            const float hn = og * tanhf(cn);
            _Float16 hf = (_Float16)hn;
            ushort_t hb; __builtin_memcpy(&hb, &hf, 2);
            // publish FIRST: get the word onto the fabric ASAP
            const uint_t word = ((uint_t)hb << 16) | (uint_t)(t + 1);
            __hip_atomic_store(&hpk[(size_t)(t & 1) * B_DIM * H_DIM + b * H_DIM + jglob],
                               word, __ATOMIC_RELAXED, __HIP_MEMORY_SCOPE_AGENT);
            c_s[tid] = cn;
            hs16[jglob] = hb;
            h_all[((size_t)b * T_DIM + t) * H_DIM + jglob] = hn;
        }

        // ---- prefetch next Xproj (overlaps spin) ----
        if (t + 1 < T_DIM) {
            if (half == 0) xv = Xproj[((size_t)b * T_DIM + (t + 1)) * XO_DIM + jg];
            if (tid < 24 && (tid & 3) == 0) xvm = Xproj[((size_t)b * T_DIM + (t + 1)) * XO_DIM + (tid >> 2)];
        }

        // ---- consume 288 foreign h words (exact-tag spin, agent scope) ----
        if (t + 1 < T_DIM) {
            if (tid >= 96 && tid < 384) {
                const uint_t want = (uint_t)(t + 1);
                uint_t* addr = &hpk[(size_t)(t & 1) * B_DIM * H_DIM + b * H_DIM + j_sp];
                uint_t v = __hip_atomic_load(addr, __ATOMIC_RELAXED, __HIP_MEMORY_SCOPE_AGENT);
                while ((v & 0xFFFFu) != want) {
                    __builtin_amdgcn_s_sleep(1);
                    v = __hip_atomic_load(addr, __ATOMIC_RELAXED, __HIP_MEMORY_SCOPE_AGENT);
                }
                hs16[j_sp] = (ushort_t)(v >> 16);
            }
            __syncthreads();
        }
    }
}

// ---------------------------------------------------------------------------
// post-pass: local_dis softmax + theme MLP, with LDS ring for the h window.
// 256 blocks x 256 threads; block = (b, 64 consecutive t).
// ---------------------------------------------------------------------------
__global__ __launch_bounds__(256, 2)
void locdis2_kernel(const float* __restrict__ h_all, const float* __restrict__ dis_all,
                    const float* __restrict__ scale_w, const float* __restrict__ scale_b,
                    const float* __restrict__ rescale_w, const float* __restrict__ rescale_b,
                    float* __restrict__ ldw, ushort_t* __restrict__ theme)
{
    __shared__ float ring[10][H_DIM];
    __shared__ float ld_all[64][10];
    __shared__ uint_t mh2[192];
    __shared__ float part_s[4][64];
    __shared__ float hid[64];
    __shared__ uint_t hid2[32];

    const int tid = threadIdx.x;
    const int b = blockIdx.x >> 2, t0 = (blockIdx.x & 3) * 64;

    const int o1 = tid & 63, p1 = tid >> 6;
    uint_t w1[48];
#pragma unroll
    for (int kk = 0; kk < 48; ++kk) {
        const int p = p1 * 48 + kk;
        w1[kk] = pkf16(scale_w[(size_t)(2 * p) * 64 + o1], scale_w[(size_t)(2 * p + 1) * 64 + o1]);
    }
    uint_t w2[48];
#pragma unroll
    for (int j = 0; j < 3; ++j) {
        const int o2 = j * 128 + (tid >> 1), hf = tid & 1;
#pragma unroll
        for (int kk = 0; kk < 16; ++kk) {
            const int p = hf * 16 + kk;
            w2[j * 16 + kk] = pkf16(rescale_w[(size_t)(2 * p) * H_DIM + o2],
                                    rescale_w[(size_t)(2 * p + 1) * H_DIM + o2]);
        }
    }

    if (tid < 64) {
        const int t = t0 + tid;
        float cum = 0.f, c[10];
        for (int wq = 0; wq < 10; ++wq) {
            const int tp = t - 9 + wq;
            cum += (tp >= 0) ? dis_all[b * T_DIM + tp] : 0.f;
            c[wq] = cum;
        }
        float mx = c[0];
        for (int wq = 1; wq < 10; ++wq) mx = fmaxf(mx, c[wq]);
        float s = 0.f, e[10];
        for (int wq = 0; wq < 10; ++wq) { e[wq] = expf(c[wq] - mx); s += e[wq]; }
        const float inv = 1.f / s;
        for (int wq = 0; wq < 10; ++wq) {
            ld_all[tid][wq] = e[wq] * inv;
            ldw[((size_t)b * T_DIM + t) * W_WIN + wq] = e[wq] * inv;
        }
    }
    for (int tp = t0 - 9; tp < t0; ++tp) {
        if (tp >= 0) {
            for (int i = tid; i < H_DIM; i += 256)
                ring[tp % 10][i] = h_all[((size_t)b * T_DIM + tp) * H_DIM + i];
        }
    }
    __syncthreads();

    for (int r = 0; r < 64; ++r) {
        const int t = t0 + r;
        if (tid < 192) {
            const float2 h2 = *(const float2*)&h_all[((size_t)b * T_DIM + t) * H_DIM + 2 * tid];
            *(float2*)&ring[t % 10][2 * tid] = h2;
        }
        __syncthreads();
        if (tid < 192) {
            float a0 = 0.f, a1 = 0.f;
            for (int wq = 0; wq < 10; ++wq) {
                const int tp = t - 9 + wq;
                if (tp >= 0) {
                    const float lw = ld_all[r][wq];
                    a0 += lw * ring[tp % 10][2 * tid];
                    a1 += lw * ring[tp % 10][2 * tid + 1];
                }
            }
            mh2[tid] = pkf16(a0 * 0.1f, a1 * 0.1f);
        }
        __syncthreads();
        {
            float acc = 0.f;
#pragma unroll
            for (int kk = 0; kk < 48; ++kk)
                acc = dot2f(w1[kk], mh2[p1 * 48 + kk], acc);
            part_s[p1][o1] = acc;
        }
        __syncthreads();
        if (tid < 64)
            hid[tid] = fmaxf(scale_b[tid] + part_s[0][tid] + part_s[1][tid] + part_s[2][tid] + part_s[3][tid], 0.f);
        __syncthreads();
        if (tid < 32) hid2[tid] = pkf16(hid[2 * tid], hid[2 * tid + 1]);
        __syncthreads();
#pragma unroll
        for (int j = 0; j < 3; ++j) {
            const int o2 = j * 128 + (tid >> 1), hf = tid & 1;
            float acc = 0.f;
#pragma unroll
            for (int kk = 0; kk < 16; ++kk)
                acc = dot2f(w2[j * 16 + kk], hid2[hf * 16 + kk], acc);
            acc += __shfl_xor(acc, 1);
            if (hf == 0)
                theme[((size_t)b * T_DIM + t) * H_DIM + o2] = f2bf(sigmoidf_(acc + rescale_b[o2]));
        }
        __syncthreads();
    }
}

// ---------------------------------------------------------------------------
extern "C" void kernel_launch(void* const* d_in, const int* in_sizes, int n_in,
                              void* d_out, int out_size, void* d_ws, size_t ws_size,
                              hipStream_t stream)
{
    const float* x         = (const float*)d_in[0];
    const float* dia_w     = (const float*)d_in[1];
    const float* dia_b     = (const float*)d_in[2];
    const float* kernel_w  = (const float*)d_in[3];
    const float* kernel_b  = (const float*)d_in[4];
    const float* rec_w     = (const float*)d_in[5];
    const float* rec_b     = (const float*)d_in[6];
    const float* scale_w   = (const float*)d_in[7];
    const float* scale_b   = (const float*)d_in[8];
    const float* rescale_w = (const float*)d_in[9];
    const float* rescale_b = (const float*)d_in[10];
    const float* conv_w    = (const float*)d_in[11];
    const float* conv_b    = (const float*)d_in[12];
    const float* out_w     = (const float*)d_in[13];
    const float* out_b     = (const float*)d_in[14];
    (void)in_sizes; (void)n_in; (void)out_size; (void)ws_size;

    float* ws = (float*)d_ws;
    size_t off = 0;
    float* Xproj   = ws + off; off += (size_t)M_DIM * XO_DIM;
    float* h_all   = ws + off; off += (size_t)M_DIM * H_DIM;
    float* ldw     = ws + off; off += (size_t)M_DIM * W_WIN;
    float* dis_all = ws + off; off += M_DIM;
    float* bias2p  = ws + off; off += XO_PAD;
    float* outbp   = ws + off; off += N_OUTP;
    uint_t* hpk    = (uint_t*)(ws + off); off += (size_t)2 * B_DIM * H_DIM;
    ushort_t* us = (ushort_t*)(ws + off);
    size_t uo = 0;
    ushort_t* dia_hi = us + uo; uo += (size_t)H_DIM * K_X;
    ushort_t* ker_hi = us + uo; uo += (size_t)XO_PAD * H_DIM;
    ushort_t* conv_t = us + uo; uo += (size_t)H_DIM * KCONV;
    ushort_t* outw_t = us + uo; uo += (size_t)N_OUTP * H_DIM;
    ushort_t* ehi    = us + uo; uo += (size_t)M_DIM * H_DIM;
    ushort_t* elo    = us + uo; uo += (size_t)M_DIM * H_DIM;
    ushort_t* themeb = us + uo; uo += (size_t)M_DIM * H_DIM;
    ushort_t* rnnb   = us + uo; uo += (size_t)M_DIM * H_DIM;
    uint_t* recg = (uint_t*)(us + uo); uo += (size_t)2 * 4 * 2 * 96 * 384;
    uint_t* recm = (uint_t*)(us + uo); uo += (size_t)2 * 6 * 192;

    // xb (bf16 x, [M][K_X]) aliases Xproj: dead before GEMM1 writes Xproj.
    ushort_t* xb = (ushort_t*)Xproj;

    // --- prep ---
    prep_x   <<<(M_DIM * (K_X / 8) + 255) / 256, 256, 0, stream>>>(x, xb);
    prep_dia <<<(H_DIM * K_X + 255) / 256, 256, 0, stream>>>(dia_w, dia_hi);
    prep_ker <<<(XO_PAD * H_DIM + 255) / 256, 256, 0, stream>>>(kernel_w, ker_hi);
    prep_conv<<<(H_DIM * KCONV + 255) / 256, 256, 0, stream>>>(conv_w, conv_t);
    prep_out <<<(N_OUTP * H_DIM + 255) / 256, 256, 0, stream>>>(out_w, outw_t);
    prep_misc<<<(N_OUTP + 255) / 256, 256, 0, stream>>>(kernel_w, kernel_b, rec_w, rec_b, out_b, bias2p, outbp);
    prep_rec2<<<(4 * 2 * 96 * 384 + 6 * 192 + 255) / 256, 256, 0, stream>>>(rec_w, recg, recm);

    // --- embed = xb @ dia_w + dia_b  (direct A, 1 pass, Ehi/Elo output) ---
    mfma_gemm<0><<<dim3(3, 128), 256, 0, stream>>>(
        xb, dia_hi, nullptr, ehi, elo,
        dia_b, nullptr, nullptr, nullptr, K_X / 32, K_X, K_X);

    // --- Xproj = embed @ kernel_w + bias2  (256-tile, A hi/lo 2 passes) ---
    mfma_gemm256<1><<<dim3(13, 64), 512, 0, stream>>>(
        ehi, elo, ker_hi, Xproj, bias2p, H_DIM / 32, H_DIM, H_DIM, XO_DIM, XO_DIM);

    // --- persistent recurrence (cooperative: co-residency guaranteed) ---
    {
        void* args[] = { (void*)&Xproj, (void*)&recg, (void*)&recm,
                         (void*)&h_all, (void*)&dis_all, (void*)&hpk };
        (void)hipLaunchCooperativeKernel((const void*)scan_kernel, dim3(256), dim3(768), args, 0, stream);
    }

    // --- local_dis + theme post-pass ---
    locdis2_kernel<<<256, 256, 0, stream>>>(
        h_all, dis_all, scale_w, scale_b, rescale_w, rescale_b, ldw, themeb);

    // --- rnn_bf = bf16( (local_h . conv_w + conv_b) * theme + h_all ) ---
    mfma_gemm<2><<<dim3(3, 128), 256, 0, stream>>>(
        nullptr, conv_t, rnnb, nullptr, nullptr,
        conv_b, themeb, h_all, ldw, KCONV / 32, KCONV, 0);

    // --- out = rnn @ out_w + out_b  (256-tile) ---
    mfma_gemm256<3><<<dim3(16, 64), 512, 0, stream>>>(
        rnnb, nullptr, outw_t, (float*)d_out, outbp, H_DIM / 32, H_DIM, H_DIM, ICD_DIM, ICD_DIM);
}

// Round 12
// 1318.680 us; speedup vs baseline: 6.5220x; 1.0283x over previous
//
#include <hip/hip_runtime.h>
#include <hip/hip_bf16.h>
#include <cstdint>
#include <cstddef>

#define B_DIM   64
#define T_DIM   256
#define ICD_DIM 2000
#define H_DIM   384
#define CH_DIM  128
#define W_WIN   10
#define M_DIM   (B_DIM * T_DIM)         // 16384
#define XO_DIM  1542                    // 4H + 2L
#define XO_PAD  1664                    // 13*128
#define K_X     2016                    // 2000 padded to 63*32
#define KCONV   3840                    // H*W
#define N_OUTP  2048                    // 2000 padded to 16*128

typedef unsigned short ushort_t;
typedef unsigned int   uint_t;
typedef __attribute__((ext_vector_type(8))) short short8;
typedef __attribute__((ext_vector_type(4))) float f32x4;
typedef __attribute__((ext_vector_type(2))) _Float16 f16x2;

__device__ __forceinline__ ushort_t f2bf(float v) {
    __hip_bfloat16 b = __float2bfloat16(v);
    ushort_t u; __builtin_memcpy(&u, &b, 2); return u;
}
__device__ __forceinline__ float bf2f(ushort_t u) {
    __hip_bfloat16 b; __builtin_memcpy(&b, &u, 2); return __bfloat162float(b);
}
__device__ __forceinline__ uint_t pk2bf(float a, float b) {
    return (uint_t)f2bf(a) | ((uint_t)f2bf(b) << 16);
}
__device__ __forceinline__ float sigmoidf_(float x) { return 1.f / (1.f + expf(-x)); }
__device__ __forceinline__ f16x2 asf16x2(uint_t u) { f16x2 h; __builtin_memcpy(&h, &u, 4); return h; }
__device__ __forceinline__ uint_t pkf16(float a, float b) {
    f16x2 h; h.x = (_Float16)a; h.y = (_Float16)b;
    uint_t u; __builtin_memcpy(&u, &h, 4); return u;
}
__device__ __forceinline__ float dot2f(uint_t a, uint_t b, float acc) {
#if __has_builtin(__builtin_amdgcn_fdot2)
    return __builtin_amdgcn_fdot2(asf16x2(a), asf16x2(b), acc, false);
#else
    f16x2 ha = asf16x2(a), hb = asf16x2(b);
    return acc + (float)ha.x * (float)hb.x + (float)ha.y * (float)hb.y;
#endif
}

// async global -> LDS, 16 bytes per lane (wave-uniform base + lane*16)
#define GLOAD_LDS16(g, l) __builtin_amdgcn_global_load_lds( \
    (const __attribute__((address_space(1))) void*)(g),     \
    (__attribute__((address_space(3))) void*)(l), 16, 0, 0)

// ---------------------------------------------------------------------------
// prep kernels
// ---------------------------------------------------------------------------
// x (f32, [M][2000]) -> xb (bf16, [M][2016], zero-padded)
__global__ void prep_x(const float* __restrict__ x, ushort_t* __restrict__ xb)
{
    int id = blockIdx.x * 256 + threadIdx.x;
    if (id >= M_DIM * (K_X / 8)) return;
    const int m = id / (K_X / 8), c = id - m * (K_X / 8);
    const int k = c * 8;
    uint_t o[4];
    if (k + 7 < ICD_DIM) {
        const float* p = x + (size_t)m * ICD_DIM + k;
        const float4 a = *(const float4*)p;
        const float4 b = *(const float4*)(p + 4);
        o[0] = pk2bf(a.x, a.y); o[1] = pk2bf(a.z, a.w);
        o[2] = pk2bf(b.x, b.y); o[3] = pk2bf(b.z, b.w);
    } else {
        float v[8];
#pragma unroll
        for (int i = 0; i < 8; ++i)
            v[i] = (k + i < ICD_DIM) ? x[(size_t)m * ICD_DIM + k + i] : 0.f;
        o[0] = pk2bf(v[0], v[1]); o[1] = pk2bf(v[2], v[3]);
        o[2] = pk2bf(v[4], v[5]); o[3] = pk2bf(v[6], v[7]);
    }
    *(uint4*)&xb[(size_t)m * K_X + k] = make_uint4(o[0], o[1], o[2], o[3]);
}

// all weight transforms in one grid-stride launch
#define PW_S0 (H_DIM * K_X)              // dia
#define PW_S1 (XO_PAD * H_DIM)           // ker
#define PW_S2 (H_DIM * KCONV)            // conv
#define PW_S3 (N_OUTP * H_DIM)           // out
#define PW_S4 (N_OUTP)                   // misc (bias2p + outbp)
#define PW_S5 (4 * 2 * 96 * 384)         // recg
#define PW_S6 (6 * 192)                  // recm
#define PW_TOT (PW_S0 + PW_S1 + PW_S2 + PW_S3 + PW_S4 + PW_S5 + PW_S6)

__global__ void prep_weights(const float* __restrict__ dia_w, const float* __restrict__ kernel_w,
                             const float* __restrict__ rec_w, const float* __restrict__ conv_w,
                             const float* __restrict__ out_w,
                             const float* __restrict__ kernel_b, const float* __restrict__ rec_b,
                             const float* __restrict__ out_b,
                             ushort_t* __restrict__ dia_hi, ushort_t* __restrict__ ker_hi,
                             ushort_t* __restrict__ conv_t, ushort_t* __restrict__ outw_t,
                             float* __restrict__ bias2p, float* __restrict__ outbp,
                             uint_t* __restrict__ recg, uint_t* __restrict__ recm)
{
    int id = blockIdx.x * 256 + threadIdx.x;
    if (id < PW_S0) {
        int n = id / K_X, k = id - n * K_X;
        dia_hi[id] = f2bf((k < ICD_DIM) ? dia_w[(size_t)k * H_DIM + n] : 0.f);
        return;
    }
    id -= PW_S0;
    if (id < PW_S1) {
        int n = id / H_DIM, k = id - n * H_DIM;
        ker_hi[id] = f2bf((n < XO_DIM) ? kernel_w[(size_t)k * XO_DIM + n] : 0.f);
        return;
    }
    id -= PW_S1;
    if (id < PW_S2) {
        int o = id / KCONV, k = id - o * KCONV;
        int w = k / H_DIM, h = k - w * H_DIM;
        conv_t[id] = f2bf(conv_w[((size_t)o * H_DIM + h) * W_WIN + w]);
        return;
    }
    id -= PW_S2;
    if (id < PW_S3) {
        int n = id / H_DIM, k = id - n * H_DIM;
        outw_t[id] = f2bf((n < ICD_DIM) ? out_w[(size_t)k * ICD_DIM + n] : 0.f);
        return;
    }
    id -= PW_S3;
    if (id < PW_S4) {
        int j = id;
        if (j < XO_PAD)
            bias2p[j] = (j < XO_DIM) ? (kernel_w[(size_t)H_DIM * XO_DIM + j] + kernel_b[j]
                                      + rec_w[(size_t)H_DIM * XO_DIM + j] + rec_b[j]) : 0.f;
        outbp[j] = (j < ICD_DIM) ? out_b[j] : 0.f;
        return;
    }
    id -= PW_S4;
    if (id < PW_S5) {
        int cg = id % 384;
        int kk = (id / 384) % 96;
        int half = (id / (384 * 96)) & 1;
        int q = id / (384 * 96 * 2);
        int p = half * 96 + kk;
        int j = 6 + (cg >> 5) * 128 + q * 32 + (cg & 31);
        recg[id] = pkf16(rec_w[(size_t)(2 * p) * XO_DIM + j], rec_w[(size_t)(2 * p + 1) * XO_DIM + j]);
        return;
    }
    id -= PW_S5;
    if (id < PW_S6) {
        int mc = id / 192, p = id % 192;
        recm[id] = pkf16(rec_w[(size_t)(2 * p) * XO_DIM + mc], rec_w[(size_t)(2 * p + 1) * XO_DIM + mc]);
    }
}

// ---------------------------------------------------------------------------
// MFMA bf16 GEMM, 128x128 tile, BK=32, 256 threads.
// MODE 0: A = xb (bf16, direct gload_lds), B = dia_hi, out Ehi/Elo split
// MODE 2: A = local_h synth (linear-addr form), B = convT, theme epilogue
// ---------------------------------------------------------------------------
template<int MODE>
__global__ __launch_bounds__(256)
void mfma_gemm(const ushort_t* __restrict__ Ab,
               const ushort_t* __restrict__ Bh,
               ushort_t* __restrict__ Cb,
               ushort_t* __restrict__ Ehi, ushort_t* __restrict__ Elo,
               const float* __restrict__ bias,
               const ushort_t* __restrict__ theme,
               const float* __restrict__ hall, const float* __restrict__ ldwp,
               int ksteps, int kdim, int astride)
{
    __shared__ ushort_t AhS[4096];
    __shared__ ushort_t BhS[4096];

    const int tid = threadIdx.x;
    const int rc = tid & 127, kh = tid >> 7;
    const int m0 = blockIdx.y * 128, n0 = blockIdx.x * 128;
    const int kq0 = kh * 2;

    const int lane = tid & 63, wid = tid >> 6;
    const int wm = wid >> 1, wn = wid & 1;
    const int l15 = lane & 15, lkq = lane >> 4;

    // MODE 2: per-thread row constants (A addr is linear in k16)
    float lw10[10];
    const float* hrow = nullptr;
    int tt_m2 = 0;
    if constexpr (MODE == 2) {
        const int gm = m0 + rc, b = gm >> 8;
        tt_m2 = gm & 255;
        hrow = hall + ((size_t)(b * T_DIM + tt_m2) - (W_WIN - 1)) * H_DIM;
#pragma unroll
        for (int w = 0; w < 10; ++w) lw10[w] = ldwp[(size_t)gm * W_WIN + w];
    }

    f32x4 acc[4][4];
#pragma unroll
    for (int i = 0; i < 4; ++i)
#pragma unroll
        for (int j = 0; j < 4; ++j)
#pragma unroll
            for (int q = 0; q < 4; ++q) acc[i][j][q] = 0.f;

    for (int ks = 0; ks < ksteps; ++ks) {
        const int k16 = ks * 32 + kh * 16;
        __syncthreads();

        // ---------------- A stage ----------------
        if constexpr (MODE == 0) {
            const ushort_t* ap = Ab + (size_t)(m0 + rc) * astride + k16;
            GLOAD_LDS16(ap,     &AhS[(kq0 * 128 + rc) * 8]);
            GLOAD_LDS16(ap + 8, &AhS[((kq0 + 1) * 128 + rc) * 8]);
        } else {
            const int w = k16 / H_DIM;
            uint_t hh[8];
            if (tt_m2 + w >= W_WIN - 1) {
                const float lw = lw10[w];
                const float* ap = hrow + k16;
#pragma unroll
                for (int qq = 0; qq < 4; ++qq) {
                    float4 t = *(const float4*)(ap + qq * 4);
                    hh[qq * 2]     = pk2bf(t.x * lw, t.y * lw);
                    hh[qq * 2 + 1] = pk2bf(t.z * lw, t.w * lw);
                }
            } else {
#pragma unroll
                for (int i = 0; i < 8; ++i) hh[i] = 0u;
            }
            *(uint4*)&AhS[(kq0 * 128 + rc) * 8]       = make_uint4(hh[0], hh[1], hh[2], hh[3]);
            *(uint4*)&AhS[((kq0 + 1) * 128 + rc) * 8] = make_uint4(hh[4], hh[5], hh[6], hh[7]);
        }

        // ---------------- B stage (async direct) ----------------
        {
            const ushort_t* bp = Bh + (size_t)(n0 + rc) * kdim + k16;
            GLOAD_LDS16(bp,     &BhS[(kq0 * 128 + rc) * 8]);
            GLOAD_LDS16(bp + 8, &BhS[((kq0 + 1) * 128 + rc) * 8]);
        }
        __syncthreads();

        // ---------------- MFMA ----------------
        short8 ah[4], bh[4];
#pragma unroll
        for (int mf = 0; mf < 4; ++mf)
            ah[mf] = *(const short8*)&AhS[(lkq * 128 + wm * 64 + mf * 16 + l15) * 8];
#pragma unroll
        for (int nf = 0; nf < 4; ++nf)
            bh[nf] = *(const short8*)&BhS[(lkq * 128 + wn * 64 + nf * 16 + l15) * 8];
#pragma unroll
        for (int mf = 0; mf < 4; ++mf)
#pragma unroll
            for (int nf = 0; nf < 4; ++nf)
                acc[mf][nf] = __builtin_amdgcn_mfma_f32_16x16x32_bf16(ah[mf], bh[nf], acc[mf][nf], 0, 0, 0);
    }

    // ---------------- epilogue ----------------
#pragma unroll
    for (int mf = 0; mf < 4; ++mf)
#pragma unroll
        for (int nf = 0; nf < 4; ++nf)
#pragma unroll
            for (int j = 0; j < 4; ++j) {
                const int gm = m0 + wm * 64 + mf * 16 + lkq * 4 + j;
                const int gn = n0 + wn * 64 + nf * 16 + l15;
                float v = acc[mf][nf][j] + bias[gn];
                if constexpr (MODE == 0) {
                    ushort_t h = f2bf(v);
                    Ehi[(size_t)gm * H_DIM + gn] = h;
                    Elo[(size_t)gm * H_DIM + gn] = f2bf(v - bf2f(h));
                } else {
                    const size_t ix = (size_t)gm * H_DIM + gn;
                    v = v * bf2f(theme[ix]) + hall[ix];
                    Cb[ix] = f2bf(v);
                }
            }
}

// ---------------------------------------------------------------------------
// MFMA bf16 GEMM, 256x128 tile, BK=32, 512 threads (8 waves, 4m x 2n).
// MODE 1: A = Ehi/Elo (2 passes), B = ker_hi, out Xproj f32 (+bias)
// MODE 3: A = rnnb (1 pass),      B = outw_t, out d_out f32 (+bias)
// ---------------------------------------------------------------------------
template<int MODE>
__global__ __launch_bounds__(512)
void mfma_gemm256(const ushort_t* __restrict__ Ah, const ushort_t* __restrict__ Al,
                  const ushort_t* __restrict__ Bm, float* __restrict__ Cf,
                  const float* __restrict__ bias,
                  int ksteps, int kdim, int astride, int ncols, int cld)
{
    constexpr bool SPLITA = (MODE == 1);
    __shared__ ushort_t AhS[8192];
    __shared__ ushort_t AlS[SPLITA ? 8192 : 16];
    __shared__ ushort_t BhS[4096];

    const int tid = threadIdx.x;
    const int m0 = blockIdx.y * 256, n0 = blockIdx.x * 128;

    const int arow = tid & 255, akh = tid >> 8;
    const int akq0 = akh * 2;
    const int bcol = tid & 127, bkq = tid >> 7;

    const int lane = tid & 63, wid = tid >> 6;
    const int wm = wid >> 1, wn = wid & 1;
    const int l15 = lane & 15, lkq = lane >> 4;

    f32x4 acc[4][4];
#pragma unroll
    for (int i = 0; i < 4; ++i)
#pragma unroll
        for (int j = 0; j < 4; ++j)
#pragma unroll
            for (int q = 0; q < 4; ++q) acc[i][j][q] = 0.f;

    for (int ks = 0; ks < ksteps; ++ks) {
        const int kb = ks * 32;
        __syncthreads();
        {
            const ushort_t* ap = Ah + (size_t)(m0 + arow) * astride + kb + akh * 16;
            GLOAD_LDS16(ap,     &AhS[((akq0 + 0) * 256 + arow) * 8]);
            GLOAD_LDS16(ap + 8, &AhS[((akq0 + 1) * 256 + arow) * 8]);
            if constexpr (SPLITA) {
                const ushort_t* ap2 = Al + (size_t)(m0 + arow) * astride + kb + akh * 16;
                GLOAD_LDS16(ap2,     &AlS[((akq0 + 0) * 256 + arow) * 8]);
                GLOAD_LDS16(ap2 + 8, &AlS[((akq0 + 1) * 256 + arow) * 8]);
            }
        }
        {
            const ushort_t* bp = Bm + (size_t)(n0 + bcol) * kdim + kb + bkq * 8;
            GLOAD_LDS16(bp, &BhS[(bkq * 128 + bcol) * 8]);
        }
        __syncthreads();

        short8 ah[4], al[4], bh[4];
#pragma unroll
        for (int mf = 0; mf < 4; ++mf)
            ah[mf] = *(const short8*)&AhS[(lkq * 256 + wm * 64 + mf * 16 + l15) * 8];
#pragma unroll
        for (int nf = 0; nf < 4; ++nf)
            bh[nf] = *(const short8*)&BhS[(lkq * 128 + wn * 64 + nf * 16 + l15) * 8];
        if constexpr (SPLITA) {
#pragma unroll
            for (int mf = 0; mf < 4; ++mf)
                al[mf] = *(const short8*)&AlS[(lkq * 256 + wm * 64 + mf * 16 + l15) * 8];
        }
#pragma unroll
        for (int mf = 0; mf < 4; ++mf)
#pragma unroll
            for (int nf = 0; nf < 4; ++nf) {
                acc[mf][nf] = __builtin_amdgcn_mfma_f32_16x16x32_bf16(ah[mf], bh[nf], acc[mf][nf], 0, 0, 0);
                if constexpr (SPLITA)
                    acc[mf][nf] = __builtin_amdgcn_mfma_f32_16x16x32_bf16(al[mf], bh[nf], acc[mf][nf], 0, 0, 0);
            }
    }

#pragma unroll
    for (int mf = 0; mf < 4; ++mf)
#pragma unroll
        for (int nf = 0; nf < 4; ++nf)
#pragma unroll
            for (int j = 0; j < 4; ++j) {
                const int gm = m0 + wm * 64 + mf * 16 + lkq * 4 + j;
                const int gn = n0 + wn * 64 + nf * 16 + l15;
                if (gn < ncols)
                    Cf[(size_t)gm * cld + gn] = acc[mf][nf][j] + bias[gn];
            }
}

// ---------------------------------------------------------------------------
// persistent scan: 256 blocks = 4 col-quarters x 64 batches, 768 threads.
// round-5 exchange protocol (proven): tag-packed f16 words, relaxed
// agent-scope atomics both sides, exact-tag spin. publish-first ordering.
// ---------------------------------------------------------------------------
__global__ __launch_bounds__(768, 3)
void scan_kernel(const float* __restrict__ Xproj, const uint_t* __restrict__ recg,
                 const uint_t* __restrict__ recm, float* __restrict__ h_all,
                 float* __restrict__ dis_all, uint_t* __restrict__ hpk)
{
    __shared__ ushort_t hs16[H_DIM];        // h_{t-1} as f16
    __shared__ float xo_s[384];             // gate cols (local index)
    __shared__ uint_t wm2[6 * 192];         // master weights (f16 pairs)
    __shared__ float c_s[96];
    __shared__ float fm_s[3], im_s[3];

    const int tid = threadIdx.x;
    const int q = blockIdx.x >> 6, b = blockIdx.x & 63;

    const int cg = tid >> 1, half = tid & 1;
    const int jg = 6 + (cg >> 5) * 128 + q * 32 + (cg & 31);

    const int gl = tid / 32, gu = tid & 31;
    const int jglob = gl * 128 + q * 32 + gu;

    const int rsp = tid - 96;
    const int qq_sp = (q + 1 + rsp / 96) & 3;
    const int s_sp = rsp % 96;
    const int j_sp = (s_sp >> 5) * 128 + qq_sp * 32 + (s_sp & 31);

    for (int i = tid; i < 6 * 192; i += 768) wm2[i] = recm[i];
    if (tid < H_DIM) hs16[tid] = 0;
    if (tid < 96) c_s[tid] = 0.f;

    uint_t w[96];
#pragma unroll
    for (int kk = 0; kk < 96; ++kk)
        w[kk] = recg[(size_t)((q * 2 + half) * 96 + kk) * 384 + cg];

    float xv = 0.f, xvm = 0.f;
    if (half == 0) xv = Xproj[((size_t)b * T_DIM + 0) * XO_DIM + jg];
    if (tid < 24 && (tid & 3) == 0) xvm = Xproj[((size_t)b * T_DIM + 0) * XO_DIM + (tid >> 2)];

    __syncthreads();

    for (int t = 0; t < T_DIM; ++t) {
        // ---- matvec: xo = Xproj + h @ rec_w (all 768 threads) ----
        {
            float acc = 0.f;
            const ushort_t* hp = &hs16[half * 192];
#pragma unroll
            for (int kk = 0; kk < 96; kk += 4) {
                const uint4 hq = *(const uint4*)(hp + kk * 2);
                acc = dot2f(w[kk + 0], hq.x, acc);
                acc = dot2f(w[kk + 1], hq.y, acc);
                acc = dot2f(w[kk + 2], hq.z, acc);
                acc = dot2f(w[kk + 3], hq.w, acc);
            }
            acc += __shfl_xor(acc, 1);
            if (half == 0) xo_s[cg] = acc + xv;
        }

        // ---- master cols + softmax, fully inside wave 0 ----
        if (tid < 64) {
            float acc = 0.f;
            if (tid < 24) {
                const int mc = tid >> 2, kq = tid & 3;
                const uint_t* wp = &wm2[mc * 192 + kq * 48];
#pragma unroll
                for (int kk = 0; kk < 48; kk += 4) {
                    const uint4 hq = *(const uint4*)&hs16[(kq * 48 + kk) * 2];
                    acc = dot2f(wp[kk + 0], hq.x, acc);
                    acc = dot2f(wp[kk + 1], hq.y, acc);
                    acc = dot2f(wp[kk + 2], hq.z, acc);
                    acc = dot2f(wp[kk + 3], hq.w, acc);
                }
                if ((tid & 3) == 0) acc += xvm;
            }
            acc += __shfl_xor(acc, 2);
            acc += __shfl_xor(acc, 1);
            const float m0 = __shfl(acc, 0),  m1 = __shfl(acc, 4),  m2 = __shfl(acc, 8);
            const float m3 = __shfl(acc, 12), m4 = __shfl(acc, 16), m5 = __shfl(acc, 20);
            if (tid == 0) {
                float mx = fmaxf(m0, fmaxf(m1, m2));
                float e0 = expf(m0 - mx), e1 = expf(m1 - mx), e2 = expf(m2 - mx);
                float inv = 1.f / (e0 + e1 + e2);
                const float f0 = e0 * inv, f1 = (e0 + e1) * inv;
                fm_s[0] = f0; fm_s[1] = f1; fm_s[2] = 1.f;
                mx = fmaxf(m3, fmaxf(m4, m5));
                e0 = expf(m3 - mx); e1 = expf(m4 - mx); e2 = expf(m5 - mx);
                inv = 1.f / (e0 + e1 + e2);
                im_s[0] = 1.f; im_s[1] = (e1 + e2) * inv; im_s[2] = e2 * inv;
                if (q == 0)
                    dis_all[b * T_DIM + t] = 1.f - (f0 + f1 + 1.f) * (1.f / 3.f);
            }
        }
        __syncthreads();

        // ---- gates / cell update + publish own 96 h-elements ----
        if (tid < 96) {
            const float fm = fm_s[gl], im = im_s[gl];
            const float fg = sigmoidf_(xo_s[gl * 32 + gu]);
            const float ig = sigmoidf_(xo_s[(3 + gl) * 32 + gu]);
            const float og = sigmoidf_(xo_s[(6 + gl) * 32 + gu]);
            const float ci = tanhf(xo_s[(9 + gl) * 32 + gu]);
            const float cl = c_s[tid];
            const float ov = fm * im;
            const float cn = ov * (fg * cl + ig * ci) + (fm - ov) * cl + (im - ov) * ci;
            const float hn = og * tanhf(cn);
            _Float16 hf = (_Float16)hn;
            ushort_t hb; __builtin_memcpy(&hb, &hf, 2);
            // publish FIRST: get the word onto the fabric ASAP
            const uint_t word = ((uint_t)hb << 16) | (uint_t)(t + 1);
            __hip_atomic_store(&hpk[(size_t)(t & 1) * B_DIM * H_DIM + b * H_DIM + jglob],
                               word, __ATOMIC_RELAXED, __HIP_MEMORY_SCOPE_AGENT);
            c_s[tid] = cn;
            hs16[jglob] = hb;
            h_all[((size_t)b * T_DIM + t) * H_DIM + jglob] = hn;
        }

        // ---- prefetch next Xproj (overlaps spin) ----
        if (t + 1 < T_DIM) {
            if (half == 0) xv = Xproj[((size_t)b * T_DIM + (t + 1)) * XO_DIM + jg];
            if (tid < 24 && (tid & 3) == 0) xvm = Xproj[((size_t)b * T_DIM + (t + 1)) * XO_DIM + (tid >> 2)];
        }

        // ---- consume 288 foreign h words (exact-tag spin, agent scope) ----
        if (t + 1 < T_DIM) {
            if (tid >= 96 && tid < 384) {
                const uint_t want = (uint_t)(t + 1);
                uint_t* addr = &hpk[(size_t)(t & 1) * B_DIM * H_DIM + b * H_DIM + j_sp];
                uint_t v = __hip_atomic_load(addr, __ATOMIC_RELAXED, __HIP_MEMORY_SCOPE_AGENT);
                int k = 0;
                while ((v & 0xFFFFu) != want) {
                    if (k++ > 0) __builtin_amdgcn_s_sleep(1);
                    v = __hip_atomic_load(addr, __ATOMIC_RELAXED, __HIP_MEMORY_SCOPE_AGENT);
                }
                hs16[j_sp] = (ushort_t)(v >> 16);
            }
            __syncthreads();
        }
    }
}

// ---------------------------------------------------------------------------
// post-pass: local_dis softmax + theme MLP, with LDS ring for the h window.
// 256 blocks x 256 threads; block = (b, 64 consecutive t).
// ---------------------------------------------------------------------------
__global__ __launch_bounds__(256, 2)
void locdis2_kernel(const float* __restrict__ h_all, const float* __restrict__ dis_all,
                    const float* __restrict__ scale_w, const float* __restrict__ scale_b,
                    const float* __restrict__ rescale_w, const float* __restrict__ rescale_b,
                    float* __restrict__ ldw, ushort_t* __restrict__ theme)
{
    __shared__ float ring[10][H_DIM];
    __shared__ float ld_all[64][10];
    __shared__ uint_t mh2[192];
    __shared__ float part_s[4][64];
    __shared__ float hid[64];
    __shared__ uint_t hid2[32];

    const int tid = threadIdx.x;
    const int b = blockIdx.x >> 2, t0 = (blockIdx.x & 3) * 64;

    const int o1 = tid & 63, p1 = tid >> 6;
    uint_t w1[48];
#pragma unroll
    for (int kk = 0; kk < 48; ++kk) {
        const int p = p1 * 48 + kk;
        w1[kk] = pkf16(scale_w[(size_t)(2 * p) * 64 + o1], scale_w[(size_t)(2 * p + 1) * 64 + o1]);
    }
    uint_t w2[48];
#pragma unroll
    for (int j = 0; j < 3; ++j) {
        const int o2 = j * 128 + (tid >> 1), hf = tid & 1;
#pragma unroll
        for (int kk = 0; kk < 16; ++kk) {
            const int p = hf * 16 + kk;
            w2[j * 16 + kk] = pkf16(rescale_w[(size_t)(2 * p) * H_DIM + o2],
                                    rescale_w[(size_t)(2 * p + 1) * H_DIM + o2]);
        }
    }

    if (tid < 64) {
        const int t = t0 + tid;
        float cum = 0.f, c[10];
        for (int wq = 0; wq < 10; ++wq) {
            const int tp = t - 9 + wq;
            cum += (tp >= 0) ? dis_all[b * T_DIM + tp] : 0.f;
            c[wq] = cum;
        }
        float mx = c[0];
        for (int wq = 1; wq < 10; ++wq) mx = fmaxf(mx, c[wq]);
        float s = 0.f, e[10];
        for (int wq = 0; wq < 10; ++wq) { e[wq] = expf(c[wq] - mx); s += e[wq]; }
        const float inv = 1.f / s;
        for (int wq = 0; wq < 10; ++wq) {
            ld_all[tid][wq] = e[wq] * inv;
            ldw[((size_t)b * T_DIM + t) * W_WIN + wq] = e[wq] * inv;
        }
    }
    for (int tp = t0 - 9; tp < t0; ++tp) {
        if (tp >= 0) {
            for (int i = tid; i < H_DIM; i += 256)
                ring[tp % 10][i] = h_all[((size_t)b * T_DIM + tp) * H_DIM + i];
        }
    }
    __syncthreads();

    for (int r = 0; r < 64; ++r) {
        const int t = t0 + r;
        if (tid < 192) {
            const float2 h2 = *(const float2*)&h_all[((size_t)b * T_DIM + t) * H_DIM + 2 * tid];
            *(float2*)&ring[t % 10][2 * tid] = h2;
        }
        __syncthreads();
        if (tid < 192) {
            float a0 = 0.f, a1 = 0.f;
            for (int wq = 0; wq < 10; ++wq) {
                const int tp = t - 9 + wq;
                if (tp >= 0) {
                    const float lw = ld_all[r][wq];
                    a0 += lw * ring[tp % 10][2 * tid];
                    a1 += lw * ring[tp % 10][2 * tid + 1];
                }
            }
            mh2[tid] = pkf16(a0 * 0.1f, a1 * 0.1f);
        }
        __syncthreads();
        {
            float acc = 0.f;
#pragma unroll
            for (int kk = 0; kk < 48; ++kk)
                acc = dot2f(w1[kk], mh2[p1 * 48 + kk], acc);
            part_s[p1][o1] = acc;
        }
        __syncthreads();
        if (tid < 64)
            hid[tid] = fmaxf(scale_b[tid] + part_s[0][tid] + part_s[1][tid] + part_s[2][tid] + part_s[3][tid], 0.f);
        __syncthreads();
        if (tid < 32) hid2[tid] = pkf16(hid[2 * tid], hid[2 * tid + 1]);
        __syncthreads();
#pragma unroll
        for (int j = 0; j < 3; ++j) {
            const int o2 = j * 128 + (tid >> 1), hf = tid & 1;
            float acc = 0.f;
#pragma unroll
            for (int kk = 0; kk < 16; ++kk)
                acc = dot2f(w2[j * 16 + kk], hid2[hf * 16 + kk], acc);
            acc += __shfl_xor(acc, 1);
            if (hf == 0)
                theme[((size_t)b * T_DIM + t) * H_DIM + o2] = f2bf(sigmoidf_(acc + rescale_b[o2]));
        }
        __syncthreads();
    }
}

// ---------------------------------------------------------------------------
extern "C" void kernel_launch(void* const* d_in, const int* in_sizes, int n_in,
                              void* d_out, int out_size, void* d_ws, size_t ws_size,
                              hipStream_t stream)
{
    const float* x         = (const float*)d_in[0];
    const float* dia_w     = (const float*)d_in[1];
    const float* dia_b     = (const float*)d_in[2];
    const float* kernel_w  = (const float*)d_in[3];
    const float* kernel_b  = (const float*)d_in[4];
    const float* rec_w     = (const float*)d_in[5];
    const float* rec_b     = (const float*)d_in[6];
    const float* scale_w   = (const float*)d_in[7];
    const float* scale_b   = (const float*)d_in[8];
    const float* rescale_w = (const float*)d_in[9];
    const float* rescale_b = (const float*)d_in[10];
    const float* conv_w    = (const float*)d_in[11];
    const float* conv_b    = (const float*)d_in[12];
    const float* out_w     = (const float*)d_in[13];
    const float* out_b     = (const float*)d_in[14];
    (void)in_sizes; (void)n_in; (void)out_size; (void)ws_size;

    float* ws = (float*)d_ws;
    size_t off = 0;
    float* Xproj   = ws + off; off += (size_t)M_DIM * XO_DIM;
    float* h_all   = ws + off; off += (size_t)M_DIM * H_DIM;
    float* ldw     = ws + off; off += (size_t)M_DIM * W_WIN;
    float* dis_all = ws + off; off += M_DIM;
    float* bias2p  = ws + off; off += XO_PAD;
    float* outbp   = ws + off; off += N_OUTP;
    uint_t* hpk    = (uint_t*)(ws + off); off += (size_t)2 * B_DIM * H_DIM;
    ushort_t* us = (ushort_t*)(ws + off);
    size_t uo = 0;
    ushort_t* dia_hi = us + uo; uo += (size_t)H_DIM * K_X;
    ushort_t* ker_hi = us + uo; uo += (size_t)XO_PAD * H_DIM;
    ushort_t* conv_t = us + uo; uo += (size_t)H_DIM * KCONV;
    ushort_t* outw_t = us + uo; uo += (size_t)N_OUTP * H_DIM;
    ushort_t* ehi    = us + uo; uo += (size_t)M_DIM * H_DIM;
    ushort_t* elo    = us + uo; uo += (size_t)M_DIM * H_DIM;
    ushort_t* themeb = us + uo; uo += (size_t)M_DIM * H_DIM;
    ushort_t* rnnb   = us + uo; uo += (size_t)M_DIM * H_DIM;
    uint_t* recg = (uint_t*)(us + uo); uo += (size_t)2 * 4 * 2 * 96 * 384;
    uint_t* recm = (uint_t*)(us + uo); uo += (size_t)2 * 6 * 192;

    // xb (bf16 x, [M][K_X]) aliases Xproj: dead before GEMM1 writes Xproj.
    ushort_t* xb = (ushort_t*)Xproj;

    // --- prep ---
    prep_x      <<<(M_DIM * (K_X / 8) + 255) / 256, 256, 0, stream>>>(x, xb);
    prep_weights<<<(PW_TOT + 255) / 256, 256, 0, stream>>>(
        dia_w, kernel_w, rec_w, conv_w, out_w, kernel_b, rec_b, out_b,
        dia_hi, ker_hi, conv_t, outw_t, bias2p, outbp, recg, recm);

    // --- embed = xb @ dia_w + dia_b  (direct A, 1 pass, Ehi/Elo output) ---
    mfma_gemm<0><<<dim3(3, 128), 256, 0, stream>>>(
        xb, dia_hi, nullptr, ehi, elo,
        dia_b, nullptr, nullptr, nullptr, K_X / 32, K_X, K_X);

    // --- Xproj = embed @ kernel_w + bias2  (256-tile, A hi/lo 2 passes) ---
    mfma_gemm256<1><<<dim3(13, 64), 512, 0, stream>>>(
        ehi, elo, ker_hi, Xproj, bias2p, H_DIM / 32, H_DIM, H_DIM, XO_DIM, XO_DIM);

    // --- persistent recurrence (cooperative: co-residency guaranteed) ---
    {
        void* args[] = { (void*)&Xproj, (void*)&recg, (void*)&recm,
                         (void*)&h_all, (void*)&dis_all, (void*)&hpk };
        (void)hipLaunchCooperativeKernel((const void*)scan_kernel, dim3(256), dim3(768), args, 0, stream);
    }

    // --- local_dis + theme post-pass ---
    locdis2_kernel<<<256, 256, 0, stream>>>(
        h_all, dis_all, scale_w, scale_b, rescale_w, rescale_b, ldw, themeb);

    // --- rnn_bf = bf16( (local_h . conv_w + conv_b) * theme + h_all ) ---
    mfma_gemm<2><<<dim3(3, 128), 256, 0, stream>>>(
        nullptr, conv_t, rnnb, nullptr, nullptr,
        conv_b, themeb, h_all, ldw, KCONV / 32, KCONV, 0);

    // --- out = rnn @ out_w + out_b  (256-tile) ---
    mfma_gemm256<3><<<dim3(16, 64), 512, 0, stream>>>(
        rnnb, nullptr, outw_t, (float*)d_out, outbp, H_DIM / 32, H_DIM, H_DIM, ICD_DIM, ICD_DIM);
}